// Round 13
// baseline (95.849 us; speedup 1.0000x reference)
//
#include <hip/hip_runtime.h>

typedef float f32x4 __attribute__((ext_vector_type(4)));
typedef short bf16x8 __attribute__((ext_vector_type(8)));

#define MFMA16 __builtin_amdgcn_mfma_f32_16x16x32_bf16

// ---------- bf16 conversion via HW packed cvt (RNE, 1 op / 2 values) ----------
__device__ __forceinline__ unsigned int cvtpk(float lo, float hi) {
    unsigned int r;
    asm("v_cvt_pk_bf16_f32 %0, %1, %2" : "=v"(r) : "v"(lo), "v"(hi));
    return r;
}
__device__ __forceinline__ unsigned short f2bf(float f) {
    return (unsigned short)cvtpk(f, f);
}
__device__ __forceinline__ bf16x8 cvt8(float4 a, float4 b) {
    union { bf16x8 v; unsigned int u[4]; } r;
    r.u[0] = cvtpk(a.x, a.y); r.u[1] = cvtpk(a.z, a.w);
    r.u[2] = cvtpk(b.x, b.y); r.u[3] = cvtpk(b.z, b.w);
    return r.v;
}
__device__ __forceinline__ uint2 pk4(float a, float b, float c, float d) {
    return make_uint2(cvtpk(a, b), cvtpk(c, d));
}
// XOR-16B-slot swizzle for 128B-row tiles (write & read use the same map)
__device__ __forceinline__ int swz(int row, int byteoff) {
    return row * 128 + ((((byteoff >> 4) ^ (row & 7)) << 4) | (byteoff & 15));
}

// ws layout (bytes):
//   0        : WqkvT bf16 [768][256]   (393216 B)
//   393216   : WoutT bf16 [256][256]   (131072 B)
//   524288   : bias_tab f32 [64][64]   (16384 B)
#define WS_NEED 540672
#define WOUTT_SHORT_OFF 196608

// =====================================================================
// Prep: transpose weights to bf16 n-major; expand PE to [q][j] table.
// =====================================================================
__global__ void prep_kernel(const float* __restrict__ wqkv,
                            const float* __restrict__ wout,
                            const float* __restrict__ pe,
                            unsigned short* __restrict__ wsT,
                            float* __restrict__ bias_tab)
{
    const int b = blockIdx.x, tid = threadIdx.x;
    if (b < 256) {
        const int w = tid >> 6, l = tid & 63;
        const int r = b * 4 + w;               // output row (n)
        const float* src;
        unsigned short* dst;
        int stride;
        if (r < 768) { src = wqkv + r; stride = 768; dst = wsT + (size_t)r * 256; }
        else { int n = r - 768; src = wout + n; stride = 256;
               dst = wsT + WOUTT_SHORT_OFF + (size_t)n * 256; }
        ushort4 v;
        v.x = f2bf(src[(size_t)(l * 4 + 0) * stride]);
        v.y = f2bf(src[(size_t)(l * 4 + 1) * stride]);
        v.z = f2bf(src[(size_t)(l * 4 + 2) * stride]);
        v.w = f2bf(src[(size_t)(l * 4 + 3) * stride]);
        *reinterpret_cast<ushort4*>(dst + l * 4) = v;
    } else {
        #pragma unroll
        for (int i = 0; i < 16; ++i) {
            int idx = tid + i * 256;           // q*64 + j
            int q = idx >> 6, j = idx & 63;
            int dy = (j >> 3) - (q >> 3) + 7;
            int dx = (j & 7) - (q & 7) + 7;
            bias_tab[idx] = pe[dy * 15 + dx];
        }
    }
}

// =====================================================================
// winattn9 = winattn8 (verified 68us) + P-buffer aliasing the sQ
// region: LDS 36864 -> 32768 B, raising the LDS occupancy cap to
// 5 blocks/CU. Both heads' Q-fragments are preloaded to registers,
// then one barrier, before any P write (round-11 alias discipline).
// __launch_bounds__ stays (256,4): runtime occupancy comes from
// actual VGPR(64)/LDS(32K); bounds=5 caused the round-11 spill.
// grid 4096 (2 heads/block), 256 thr.
// =====================================================================
__global__ __launch_bounds__(256, 4)
void winattn9(const float* __restrict__ x,
              const unsigned short* __restrict__ wqkvT,
              const float* __restrict__ bias_tab,
              float* __restrict__ out)
{
    __shared__ __align__(16) unsigned char smem[32768];
    typedef unsigned short (*arr40)[40];
    // GEMM-phase views (swizzled 128B rows): Xb 8192 + Wb 24576 = 32768
    unsigned char* Xb = smem;                               // [64][128B]
    unsigned char* Wb = smem + 8192;                        // [192][128B]
    // attn-phase views (alias; valid after post-GEMM barrier)
    arr40 sQ = reinterpret_cast<arr40>(smem);               // [128][40] (10240B)
    arr40 sK = reinterpret_cast<arr40>(smem + 10240);       // [128][40] (10240B)
    unsigned char* Vb = smem + 20480;                       // [64][128B] swz (8192B)
    unsigned char* Pb = smem;                               // [64][128B] swz, ALIASES sQ

    const int tid  = threadIdx.x;
    const int lane = tid & 63;
    const int wv   = tid >> 6;
    const int ln   = lane & 15;
    const int lg   = lane >> 4;

    // XCD swizzle: the 4 blocks of one window land on the same XCD
    const int L   = ((blockIdx.x & 7) << 9) + (blockIdx.x >> 3);
    const int wid = L >> 2;
    const int h0  = (L & 3) << 1;          // head pair h0, h0+1
    const int blw = wid >> 6;
    const int whr = (wid >> 3) & 7;
    const int wwc = wid & 7;
    const int tok_base = blw * 4096 + whr * 512 + wwc * 8;
    // token(i) = tok_base + (i>>3)*64 + (i&7)

    // ---- staging thread maps (T14 async-split, verified rounds 9-12) ----
    const int c8    = tid & 7;             // 16B slot within row
    const int xrow0 = tid >> 3;            // X rows 0..31
    const int xrow1 = 32 + (tid >> 3);     //        32..63
    const float* xs0 = x + (size_t)(tok_base + ((xrow0 >> 3) << 6) + (xrow0 & 7)) * 256 + c8 * 8;
    const float* xs1 = x + (size_t)(tok_base + ((xrow1 >> 3) << 6) + (xrow1 & 7)) * 256 + c8 * 8;
    const int wrb = tid >> 3;
    const unsigned short* ws0; const unsigned short* ws1;
    const unsigned short* ws2; const unsigned short* ws3;
    const unsigned short* ws4; const unsigned short* ws5;
    {
        #define WSRC(IT) ({ int r = (IT)*32 + wrb; int nt_ = r >> 4;          \
            int m_ = nt_ >> 2, hp_ = (nt_ >> 1) & 1, hf_ = nt_ & 1;           \
            int n = m_ * 256 + (h0 + hp_) * 32 + hf_ * 16 + (r & 15);         \
            wqkvT + (size_t)n * 256 + c8 * 8; })
        ws0 = WSRC(0); ws1 = WSRC(1); ws2 = WSRC(2);
        ws3 = WSRC(3); ws4 = WSRC(4); ws5 = WSRC(5);
        #undef WSRC
    }

    // ---- prologue: load chunk 0 into registers ----
    float4 xa0 = *reinterpret_cast<const float4*>(xs0);
    float4 xb0 = *reinterpret_cast<const float4*>(xs0 + 4);
    float4 xa1 = *reinterpret_cast<const float4*>(xs1);
    float4 xb1 = *reinterpret_cast<const float4*>(xs1 + 4);
    bf16x8 w0 = *reinterpret_cast<const bf16x8*>(ws0);
    bf16x8 w1 = *reinterpret_cast<const bf16x8*>(ws1);
    bf16x8 w2 = *reinterpret_cast<const bf16x8*>(ws2);
    bf16x8 w3 = *reinterpret_cast<const bf16x8*>(ws3);
    bf16x8 w4 = *reinterpret_cast<const bf16x8*>(ws4);
    bf16x8 w5 = *reinterpret_cast<const bf16x8*>(ws5);

    f32x4 acc[4][3];
    #pragma unroll
    for (int mt = 0; mt < 4; ++mt)
        #pragma unroll
        for (int jt = 0; jt < 3; ++jt) acc[mt][jt] = (f32x4)(0.f);

    #pragma unroll
    for (int kc = 0; kc < 4; ++kc) {
        // ---- write phase: regs (chunk kc) -> swizzled LDS ----
        *reinterpret_cast<bf16x8*>(Xb + swz(xrow0, c8 * 16)) = cvt8(xa0, xb0);
        *reinterpret_cast<bf16x8*>(Xb + swz(xrow1, c8 * 16)) = cvt8(xa1, xb1);
        *reinterpret_cast<bf16x8*>(Wb + swz(0 * 32 + wrb, c8 * 16)) = w0;
        *reinterpret_cast<bf16x8*>(Wb + swz(1 * 32 + wrb, c8 * 16)) = w1;
        *reinterpret_cast<bf16x8*>(Wb + swz(2 * 32 + wrb, c8 * 16)) = w2;
        *reinterpret_cast<bf16x8*>(Wb + swz(3 * 32 + wrb, c8 * 16)) = w3;
        *reinterpret_cast<bf16x8*>(Wb + swz(4 * 32 + wrb, c8 * 16)) = w4;
        *reinterpret_cast<bf16x8*>(Wb + swz(5 * 32 + wrb, c8 * 16)) = w5;
        __syncthreads();                    // (A) writes visible

        // ---- issue chunk kc+1 loads (fly under the MFMAs below) ----
        if (kc < 3) {
            const int ko = (kc + 1) * 64;
            xa0 = *reinterpret_cast<const float4*>(xs0 + ko);
            xb0 = *reinterpret_cast<const float4*>(xs0 + ko + 4);
            xa1 = *reinterpret_cast<const float4*>(xs1 + ko);
            xb1 = *reinterpret_cast<const float4*>(xs1 + ko + 4);
            w0 = *reinterpret_cast<const bf16x8*>(ws0 + ko);
            w1 = *reinterpret_cast<const bf16x8*>(ws1 + ko);
            w2 = *reinterpret_cast<const bf16x8*>(ws2 + ko);
            w3 = *reinterpret_cast<const bf16x8*>(ws3 + ko);
            w4 = *reinterpret_cast<const bf16x8*>(ws4 + ko);
            w5 = *reinterpret_cast<const bf16x8*>(ws5 + ko);
        }

        // ---- MFMA phase: wave owns all 4 m-tiles x its 3 n-tiles ----
        #pragma unroll
        for (int ks = 0; ks < 2; ++ks) {
            const int cb = ks * 64 + lg * 16;   // byte col within row
            bf16x8 a0 = *reinterpret_cast<const bf16x8*>(Xb + swz(     ln, cb));
            bf16x8 a1 = *reinterpret_cast<const bf16x8*>(Xb + swz(16 + ln, cb));
            bf16x8 a2 = *reinterpret_cast<const bf16x8*>(Xb + swz(32 + ln, cb));
            bf16x8 a3 = *reinterpret_cast<const bf16x8*>(Xb + swz(48 + ln, cb));
            #pragma unroll
            for (int jt = 0; jt < 3; ++jt) {
                bf16x8 bb = *reinterpret_cast<const bf16x8*>(
                    Wb + swz((wv * 3 + jt) * 16 + ln, cb));
                acc[0][jt] = MFMA16(a0, bb, acc[0][jt], 0, 0, 0);
                acc[1][jt] = MFMA16(a1, bb, acc[1][jt], 0, 0, 0);
                acc[2][jt] = MFMA16(a2, bb, acc[2][jt], 0, 0, 0);
                acc[3][jt] = MFMA16(a3, bb, acc[3][jt], 0, 0, 0);
            }
        }
        __syncthreads();                    // (B) MFMA reads done
    }

    // ---- epilogue: per owned n-tile (wave-uniform branch) ----
    const float scale = 0.17677669529663687f;
    #pragma unroll
    for (int jt = 0; jt < 3; ++jt) {
        const int n_t = wv * 3 + jt;
        const int m  = n_t >> 2;
        const int hp = (n_t >> 1) & 1;
        const int hf = n_t & 1;
        if (m == 0) {          // Q (pre-scaled), [tok][ch] b16 scatter
            #pragma unroll
            for (int mt = 0; mt < 4; ++mt)
                #pragma unroll
                for (int r = 0; r < 4; ++r)
                    sQ[hp * 64 + mt * 16 + lg * 4 + r][hf * 16 + ln] =
                        f2bf(acc[mt][jt][r] * scale);
        } else if (m == 1) {   // K, [tok][ch] b16 scatter
            #pragma unroll
            for (int mt = 0; mt < 4; ++mt)
                #pragma unroll
                for (int r = 0; r < 4; ++r)
                    sK[hp * 64 + mt * 16 + lg * 4 + r][hf * 16 + ln] =
                        f2bf(acc[mt][jt][r]);
        } else {               // V -> VT[ch][tok], swizzled 8B packs
            const int row = hp * 32 + hf * 16 + ln;
            #pragma unroll
            for (int mt = 0; mt < 4; ++mt)
                *reinterpret_cast<uint2*>(Vb + swz(row, mt * 32 + lg * 8)) =
                    pk4(acc[mt][jt][0], acc[mt][jt][1],
                        acc[mt][jt][2], acc[mt][jt][3]);
        }
    }
    __syncthreads();

    // ---- attention. Preload BOTH heads' Q-fragments, then barrier so
    // P (aliasing the sQ region) can be written safely. ----
    const int q = wv * 16 + ln;
    const int prow = wv * 16 + ln;
    bf16x8 qf0 = *reinterpret_cast<const bf16x8*>(&sQ[      q][lg * 8]);
    bf16x8 qf1 = *reinterpret_cast<const bf16x8*>(&sQ[64 + q][lg * 8]);
    __syncthreads();   // all Q reads done before P overwrites the region

    #pragma unroll
    for (int hp = 0; hp < 2; ++hp) {
        bf16x8 qf = hp ? qf1 : qf0;
        f32x4 st[4];
        #pragma unroll
        for (int mt = 0; mt < 4; ++mt) {
            bf16x8 kf = *reinterpret_cast<const bf16x8*>(
                &sK[hp * 64 + mt * 16 + ln][lg * 8]);
            st[mt] = MFMA16(kf, qf, (f32x4)(0.f), 0, 0, 0);
        }

        float sv[16];
        float mx = -3.0e38f;
        #pragma unroll
        for (int mt = 0; mt < 4; ++mt) {
            float4 bt = *reinterpret_cast<const float4*>(
                &bias_tab[q * 64 + mt * 16 + lg * 4]);
            float b4[4] = {bt.x, bt.y, bt.z, bt.w};
            #pragma unroll
            for (int r = 0; r < 4; ++r) {
                float s = st[mt][r] + b4[r];
                sv[mt * 4 + r] = s;
                mx = fmaxf(mx, s);
            }
        }
        mx = fmaxf(mx, __shfl_xor(mx, 16));
        mx = fmaxf(mx, __shfl_xor(mx, 32));
        float sum = 0.f;
        #pragma unroll
        for (int i = 0; i < 16; ++i) { sv[i] = __expf(sv[i] - mx); sum += sv[i]; }
        sum += __shfl_xor(sum, 16);
        sum += __shfl_xor(sum, 32);
        const float inv = 1.0f / sum;

        #pragma unroll
        for (int mt = 0; mt < 4; ++mt)
            *reinterpret_cast<uint2*>(Pb + swz(prow, mt * 32 + lg * 8)) =
                pk4(sv[mt * 4 + 0] * inv, sv[mt * 4 + 1] * inv,
                    sv[mt * 4 + 2] * inv, sv[mt * 4 + 3] * inv);

        f32x4 o[2] = {(f32x4)(0.f), (f32x4)(0.f)};
        #pragma unroll
        for (int ks = 0; ks < 2; ++ks) {
            bf16x8 pf = *reinterpret_cast<const bf16x8*>(
                Pb + swz(prow, ks * 64 + lg * 16));
            #pragma unroll
            for (int nt = 0; nt < 2; ++nt) {
                bf16x8 vf = *reinterpret_cast<const bf16x8*>(
                    Vb + swz(hp * 32 + nt * 16 + ln, ks * 64 + lg * 16));
                o[nt] = MFMA16(pf, vf, o[nt], 0, 0, 0);
            }
        }

        #pragma unroll
        for (int nt = 0; nt < 2; ++nt) {
            #pragma unroll
            for (int r = 0; r < 4; ++r) {
                int qi  = wv * 16 + lg * 4 + r;
                int tok = tok_base + ((qi >> 3) << 6) + (qi & 7);
                out[(size_t)tok * 256 + (h0 + hp) * 32 + nt * 16 + ln] = o[nt][r];
            }
        }
    }
}

// =====================================================================
// proj4: in-place out = A @ w_out + b_out (verified; cvt_pk stage).
// =====================================================================
__global__ __launch_bounds__(256, 3)
void proj4(float* __restrict__ io,
           const unsigned short* __restrict__ woutT,
           const float* __restrict__ b_out)
{
    __shared__ __align__(16) unsigned short sA[64][264];

    const int tid  = threadIdx.x;
    const int lane = tid & 63;
    const int wv   = tid >> 6;
    const int ln   = lane & 15;
    const int lg   = lane >> 4;
    const size_t m0 = (size_t)blockIdx.x * 64;

    const unsigned short* b0 = woutT + (size_t)((wv +  0) * 16 + ln) * 256 + lg * 8;
    const unsigned short* b1 = woutT + (size_t)((wv +  4) * 16 + ln) * 256 + lg * 8;
    const unsigned short* b2 = woutT + (size_t)((wv +  8) * 16 + ln) * 256 + lg * 8;
    const unsigned short* b3 = woutT + (size_t)((wv + 12) * 16 + ln) * 256 + lg * 8;
    bf16x8 bc0 = *reinterpret_cast<const bf16x8*>(b0);
    bf16x8 bc1 = *reinterpret_cast<const bf16x8*>(b1);
    bf16x8 bc2 = *reinterpret_cast<const bf16x8*>(b2);
    bf16x8 bc3 = *reinterpret_cast<const bf16x8*>(b3);

    #pragma unroll
    for (int it = 0; it < 8; ++it) {
        int idx = tid + (it << 8);
        int row = idx >> 5, c8 = idx & 31;
        const float* p = io + (m0 + row) * 256 + c8 * 8;
        float4 a = *reinterpret_cast<const float4*>(p);
        float4 b = *reinterpret_cast<const float4*>(p + 4);
        *reinterpret_cast<bf16x8*>(&sA[row][c8 * 8]) = cvt8(a, b);
    }
    __syncthreads();

    f32x4 acc[4][4];
    #pragma unroll
    for (int m = 0; m < 4; ++m)
        #pragma unroll
        for (int j = 0; j < 4; ++j) acc[m][j] = (f32x4)(0.f);

    #pragma unroll
    for (int st = 0; st < 8; ++st) {
        const int ko = st * 32 + lg * 8;
        bf16x8 a0 = *reinterpret_cast<const bf16x8*>(&sA[     ln][ko]);
        bf16x8 a1 = *reinterpret_cast<const bf16x8*>(&sA[16 + ln][ko]);
        bf16x8 a2 = *reinterpret_cast<const bf16x8*>(&sA[32 + ln][ko]);
        bf16x8 a3 = *reinterpret_cast<const bf16x8*>(&sA[48 + ln][ko]);
        bf16x8 bn0 = bc0, bn1 = bc1, bn2 = bc2, bn3 = bc3;
        if (st < 7) {
            bn0 = *reinterpret_cast<const bf16x8*>(b0 + (st + 1) * 32);
            bn1 = *reinterpret_cast<const bf16x8*>(b1 + (st + 1) * 32);
            bn2 = *reinterpret_cast<const bf16x8*>(b2 + (st + 1) * 32);
            bn3 = *reinterpret_cast<const bf16x8*>(b3 + (st + 1) * 32);
        }
        acc[0][0] = MFMA16(a0, bc0, acc[0][0], 0, 0, 0);
        acc[1][0] = MFMA16(a1, bc0, acc[1][0], 0, 0, 0);
        acc[2][0] = MFMA16(a2, bc0, acc[2][0], 0, 0, 0);
        acc[3][0] = MFMA16(a3, bc0, acc[3][0], 0, 0, 0);
        acc[0][1] = MFMA16(a0, bc1, acc[0][1], 0, 0, 0);
        acc[1][1] = MFMA16(a1, bc1, acc[1][1], 0, 0, 0);
        acc[2][1] = MFMA16(a2, bc1, acc[2][1], 0, 0, 0);
        acc[3][1] = MFMA16(a3, bc1, acc[3][1], 0, 0, 0);
        acc[0][2] = MFMA16(a0, bc2, acc[0][2], 0, 0, 0);
        acc[1][2] = MFMA16(a1, bc2, acc[1][2], 0, 0, 0);
        acc[2][2] = MFMA16(a2, bc2, acc[2][2], 0, 0, 0);
        acc[3][2] = MFMA16(a3, bc2, acc[3][2], 0, 0, 0);
        acc[0][3] = MFMA16(a0, bc3, acc[0][3], 0, 0, 0);
        acc[1][3] = MFMA16(a1, bc3, acc[1][3], 0, 0, 0);
        acc[2][3] = MFMA16(a2, bc3, acc[2][3], 0, 0, 0);
        acc[3][3] = MFMA16(a3, bc3, acc[3][3], 0, 0, 0);
        bc0 = bn0; bc1 = bn1; bc2 = bn2; bc3 = bn3;
    }

    #pragma unroll
    for (int j = 0; j < 4; ++j) {
        int nt = wv + 4 * j;
        float bias = b_out[nt * 16 + ln];
        #pragma unroll
        for (int m = 0; m < 4; ++m)
            #pragma unroll
            for (int r = 0; r < 4; ++r)
                io[(m0 + m * 16 + lg * 4 + r) * 256 + nt * 16 + ln] =
                    acc[m][j][r] + bias;
    }
}

// =====================================================================
// Fallback (round-3 verified kernels) if ws_size < WS_NEED.
// =====================================================================
__device__ __forceinline__ bf16x8 ldsFrag(const unsigned short* p) {
    return *reinterpret_cast<const bf16x8*>(p);
}

__global__ __launch_bounds__(256, 2)
void winattn_fb(const float* __restrict__ x,
                const float* __restrict__ w_qkv,
                const float* __restrict__ pe,
                float* __restrict__ attn_out)
{
    __shared__ __align__(16) unsigned short sX[64][264];
    __shared__ __align__(16) unsigned short sW[96][72];
    __shared__ __align__(16) unsigned short sQ[64][40];
    __shared__ __align__(16) unsigned short sK[64][40];
    __shared__ __align__(16) unsigned short sVT[32][72];
    __shared__ float sPE[225];
    unsigned short* sP = &sX[0][0];

    const int tid  = threadIdx.x;
    const int lane = tid & 63;
    const int wv   = tid >> 6;
    const int ln   = lane & 15;
    const int lg   = lane >> 4;

    const int h   = blockIdx.x & 7;
    const int wid = blockIdx.x >> 3;
    const int blw = wid >> 6;
    const int whr = (wid >> 3) & 7;
    const int wwc = wid & 7;
    const int tok_base = blw * 4096 + whr * 512 + wwc * 8;

    if (tid < 225) sPE[tid] = pe[tid];

    #pragma unroll
    for (int it = 0; it < 16; ++it) {
        int g = tid + (it << 8);
        int row = g >> 6, f4 = g & 63;
        int tok = tok_base + ((row >> 3) << 6) + (row & 7);
        float4 v = *reinterpret_cast<const float4*>(x + (size_t)tok * 256 + f4 * 4);
        ushort4 u;
        u.x = f2bf(v.x); u.y = f2bf(v.y); u.z = f2bf(v.z); u.w = f2bf(v.w);
        *reinterpret_cast<ushort4*>(&sX[row][f4 << 2]) = u;
    }

    auto stage_w = [&](int kc) {
        #pragma unroll
        for (int it = 0; it < 8; ++it) {
            int g = tid + (it << 8);
            int k = g >> 5, c = g & 31;
            if (c < 24) {
                int m = c >> 3, f4 = c & 7;
                float4 v = *reinterpret_cast<const float4*>(
                    w_qkv + (size_t)(kc * 64 + k) * 768 + m * 256 + h * 32 + f4 * 4);
                float vals[4] = {v.x, v.y, v.z, v.w};
                int n0 = m * 32 + f4 * 4;
                #pragma unroll
                for (int e0 = 0; e0 < 4; ++e0) {
                    int e = (e0 + lane) & 3;
                    sW[n0 + e][k] = f2bf(vals[e]);
                }
            }
        }
    };

    stage_w(0);
    __syncthreads();

    f32x4 acc[6];
    #pragma unroll
    for (int nt = 0; nt < 6; ++nt) acc[nt] = (f32x4)(0.f);

    for (int kc = 0; kc < 4; ++kc) {
        #pragma unroll
        for (int ks = 0; ks < 2; ++ks) {
            bf16x8 a = ldsFrag(&sX[wv * 16 + ln][kc * 64 + ks * 32 + lg * 8]);
            #pragma unroll
            for (int nt = 0; nt < 6; ++nt) {
                bf16x8 b = ldsFrag(&sW[nt * 16 + ln][ks * 32 + lg * 8]);
                acc[nt] = MFMA16(a, b, acc[nt], 0, 0, 0);
            }
        }
        if (kc < 3) { __syncthreads(); stage_w(kc + 1); __syncthreads(); }
    }

    #pragma unroll
    for (int nt = 0; nt < 4; ++nt)
        #pragma unroll
        for (int r = 0; r < 4; ++r) {
            int row = wv * 16 + lg * 4 + r;
            unsigned short bv = f2bf(acc[nt][r]);
            if (nt < 2) sQ[row][nt * 16 + ln] = bv;
            else        sK[row][(nt - 2) * 16 + ln] = bv;
        }
    #pragma unroll
    for (int nt = 4; nt < 6; ++nt) {
        ushort4 pv;
        pv.x = f2bf(acc[nt][0]); pv.y = f2bf(acc[nt][1]);
        pv.z = f2bf(acc[nt][2]); pv.w = f2bf(acc[nt][3]);
        *reinterpret_cast<ushort4*>(&sVT[(nt - 4) * 16 + ln][wv * 16 + lg * 4]) = pv;
    }
    __syncthreads();

    const f32x4 zero = (f32x4)(0.f);
    bf16x8 qf = ldsFrag(&sQ[wv * 16 + ln][lg * 8]);
    f32x4 st[4];
    #pragma unroll
    for (int mt = 0; mt < 4; ++mt) {
        bf16x8 kf = ldsFrag(&sK[mt * 16 + ln][lg * 8]);
        st[mt] = MFMA16(kf, qf, zero, 0, 0, 0);
    }

    const int q = wv * 16 + ln;
    const int qr = q >> 3, qc = q & 7;
    const float scale = 0.17677669529663687f;
    float sv[16];
    float mx = -3.0e38f;
    #pragma unroll
    for (int mt = 0; mt < 4; ++mt)
        #pragma unroll
        for (int r = 0; r < 4; ++r) {
            int j = mt * 16 + lg * 4 + r;
            int dy = (j >> 3) - qr + 7;
            int dx = (j & 7) - qc + 7;
            float s = st[mt][r] * scale + sPE[dy * 15 + dx];
            sv[mt * 4 + r] = s;
            mx = fmaxf(mx, s);
        }
    mx = fmaxf(mx, __shfl_xor(mx, 16));
    mx = fmaxf(mx, __shfl_xor(mx, 32));
    float sum = 0.f;
    #pragma unroll
    for (int i = 0; i < 16; ++i) { sv[i] = __expf(sv[i] - mx); sum += sv[i]; }
    sum += __shfl_xor(sum, 16);
    sum += __shfl_xor(sum, 32);
    const float inv = 1.0f / sum;

    unsigned short* sPw = sP + wv * (16 * 72) + ln * 72;
    #pragma unroll
    for (int mt = 0; mt < 4; ++mt) {
        ushort4 pv;
        pv.x = f2bf(sv[mt * 4 + 0] * inv);
        pv.y = f2bf(sv[mt * 4 + 1] * inv);
        pv.z = f2bf(sv[mt * 4 + 2] * inv);
        pv.w = f2bf(sv[mt * 4 + 3] * inv);
        *reinterpret_cast<ushort4*>(sPw + mt * 16 + lg * 4) = pv;
    }

    f32x4 o[2] = {zero, zero};
    #pragma unroll
    for (int ks = 0; ks < 2; ++ks) {
        bf16x8 pf = ldsFrag(sPw + ks * 32 + lg * 8);
        #pragma unroll
        for (int nt = 0; nt < 2; ++nt) {
            bf16x8 vf = ldsFrag(&sVT[nt * 16 + ln][ks * 32 + lg * 8]);
            o[nt] = MFMA16(pf, vf, o[nt], 0, 0, 0);
        }
    }
    #pragma unroll
    for (int nt = 0; nt < 2; ++nt)
        #pragma unroll
        for (int r = 0; r < 4; ++r) {
            int qi = wv * 16 + lg * 4 + r;
            int tok = tok_base + ((qi >> 3) << 6) + (qi & 7);
            attn_out[(size_t)tok * 256 + h * 32 + nt * 16 + ln] = o[nt][r];
        }
}

__global__ __launch_bounds__(256, 3)
void proj_fb(float* __restrict__ io,
             const float* __restrict__ w_out,
             const float* __restrict__ b_out)
{
    __shared__ __align__(16) unsigned short sA[64][72];
    __shared__ __align__(16) unsigned short sW2[256][72];
    __shared__ float sB[256];

    const int tid  = threadIdx.x;
    const int lane = tid & 63;
    const int wv   = tid >> 6;
    const int ln   = lane & 15;
    const int lg   = lane >> 4;
    const size_t m0 = (size_t)blockIdx.x * 64;

    sB[tid] = b_out[tid];

    f32x4 acc[16];
    #pragma unroll
    for (int nt = 0; nt < 16; ++nt) acc[nt] = (f32x4)(0.f);

    for (int kc = 0; kc < 4; ++kc) {
        if (kc) __syncthreads();
        #pragma unroll
        for (int it = 0; it < 4; ++it) {
            int g = tid + (it << 8);
            int row = g >> 4, f4 = g & 15;
            float4 v = *reinterpret_cast<const float4*>(
                io + (m0 + row) * 256 + kc * 64 + f4 * 4);
            ushort4 u;
            u.x = f2bf(v.x); u.y = f2bf(v.y); u.z = f2bf(v.z); u.w = f2bf(v.w);
            *reinterpret_cast<ushort4*>(&sA[row][f4 << 2]) = u;
        }
        #pragma unroll
        for (int i = 0; i < 16; ++i) {
            int f4 = ln + 16 * (i & 3);
            int kl = 16 * wv + lg + 4 * (i >> 2);
            float4 v = *reinterpret_cast<const float4*>(
                w_out + (size_t)(kc * 64 + kl) * 256 + f4 * 4);
            float vals[4] = {v.x, v.y, v.z, v.w};
            #pragma unroll
            for (int e0 = 0; e0 < 4; ++e0) {
                int e = (e0 + lane) & 3;
                sW2[f4 * 4 + e][kl] = f2bf(vals[e]);
            }
        }
        __syncthreads();

        #pragma unroll
        for (int ks = 0; ks < 2; ++ks) {
            bf16x8 a = ldsFrag(&sA[wv * 16 + ln][ks * 32 + lg * 8]);
            #pragma unroll
            for (int nt = 0; nt < 16; ++nt) {
                bf16x8 b = ldsFrag(&sW2[nt * 16 + ln][ks * 32 + lg * 8]);
                acc[nt] = MFMA16(a, b, acc[nt], 0, 0, 0);
            }
        }
    }

    #pragma unroll
    for (int nt = 0; nt < 16; ++nt) {
        float bias = sB[nt * 16 + ln];
        #pragma unroll
        for (int r = 0; r < 4; ++r) {
            int row = wv * 16 + lg * 4 + r;
            io[(m0 + row) * 256 + nt * 16 + ln] = acc[nt][r] + bias;
        }
    }
}

extern "C" void kernel_launch(void* const* d_in, const int* in_sizes, int n_in,
                              void* d_out, int out_size, void* d_ws, size_t ws_size,
                              hipStream_t stream) {
    const float* x     = (const float*)d_in[0];
    const float* w_qkv = (const float*)d_in[1];
    const float* w_out = (const float*)d_in[2];
    const float* b_out = (const float*)d_in[3];
    const float* pe    = (const float*)d_in[4];
    (void)in_sizes; (void)n_in; (void)out_size;

    float* out = (float*)d_out;

    if (ws_size >= (size_t)WS_NEED) {
        unsigned short* wsT = (unsigned short*)d_ws;
        float* bias_tab = (float*)((char*)d_ws + 524288);
        prep_kernel<<<dim3(257),  dim3(256), 0, stream>>>(w_qkv, w_out, pe, wsT, bias_tab);
        winattn9   <<<dim3(4096), dim3(256), 0, stream>>>(x, wsT, bias_tab, out);
        proj4      <<<dim3(1024), dim3(256), 0, stream>>>(out, wsT + WOUTT_SHORT_OFF, b_out);
    } else {
        winattn_fb <<<dim3(8192), dim3(256), 0, stream>>>(x, w_qkv, pe, out);
        proj_fb    <<<dim3(1024), dim3(256), 0, stream>>>(out, w_out, b_out);
    }
}

// Round 14
// 86.195 us; speedup vs baseline: 1.1120x; 1.1120x over previous
//
#include <hip/hip_runtime.h>

typedef float f32x4 __attribute__((ext_vector_type(4)));
typedef short bf16x8 __attribute__((ext_vector_type(8)));

#define MFMA16 __builtin_amdgcn_mfma_f32_16x16x32_bf16

// ---------- bf16 conversion via HW packed cvt (RNE, 1 op / 2 values) ----------
__device__ __forceinline__ unsigned int cvtpk(float lo, float hi) {
    unsigned int r;
    asm("v_cvt_pk_bf16_f32 %0, %1, %2" : "=v"(r) : "v"(lo), "v"(hi));
    return r;
}
__device__ __forceinline__ unsigned short f2bf(float f) {
    return (unsigned short)cvtpk(f, f);
}
__device__ __forceinline__ bf16x8 cvt8(float4 a, float4 b) {
    union { bf16x8 v; unsigned int u[4]; } r;
    r.u[0] = cvtpk(a.x, a.y); r.u[1] = cvtpk(a.z, a.w);
    r.u[2] = cvtpk(b.x, b.y); r.u[3] = cvtpk(b.z, b.w);
    return r.v;
}
__device__ __forceinline__ uint2 pk4(float a, float b, float c, float d) {
    return make_uint2(cvtpk(a, b), cvtpk(c, d));
}
// XOR-16B-slot swizzle for 128B-row tiles (write & read use the same map)
__device__ __forceinline__ int swz(int row, int byteoff) {
    return row * 128 + ((((byteoff >> 4) ^ (row & 7)) << 4) | (byteoff & 15));
}

// ws layout (bytes):
//   0        : WqkvT bf16 [768][256]   (393216 B)
//   393216   : WoutT bf16 [256][256]   (131072 B)
//   524288   : bias_tab f32 [64][64]   (16384 B)
//   540672   : O bf16 [65536][256]     (33554432 B)  token-major attn out
#define WS_NEED   540672
#define WS_NEED2  34095104
#define WOUTT_SHORT_OFF 196608
#define O_SHORT_OFF     270336

// =====================================================================
// Prep: transpose weights to bf16 n-major; expand PE to [q][j] table.
// =====================================================================
__global__ void prep_kernel(const float* __restrict__ wqkv,
                            const float* __restrict__ wout,
                            const float* __restrict__ pe,
                            unsigned short* __restrict__ wsT,
                            float* __restrict__ bias_tab)
{
    const int b = blockIdx.x, tid = threadIdx.x;
    if (b < 256) {
        const int w = tid >> 6, l = tid & 63;
        const int r = b * 4 + w;               // output row (n)
        const float* src;
        unsigned short* dst;
        int stride;
        if (r < 768) { src = wqkv + r; stride = 768; dst = wsT + (size_t)r * 256; }
        else { int n = r - 768; src = wout + n; stride = 256;
               dst = wsT + WOUTT_SHORT_OFF + (size_t)n * 256; }
        ushort4 v;
        v.x = f2bf(src[(size_t)(l * 4 + 0) * stride]);
        v.y = f2bf(src[(size_t)(l * 4 + 1) * stride]);
        v.z = f2bf(src[(size_t)(l * 4 + 2) * stride]);
        v.w = f2bf(src[(size_t)(l * 4 + 3) * stride]);
        *reinterpret_cast<ushort4*>(dst + l * 4) = v;
    } else {
        #pragma unroll
        for (int i = 0; i < 16; ++i) {
            int idx = tid + i * 256;           // q*64 + j
            int q = idx >> 6, j = idx & 63;
            int dy = (j >> 3) - (q >> 3) + 7;
            int dx = (j & 7) - (q & 7) + 7;
            bias_tab[idx] = pe[dy * 15 + dx];
        }
    }
}

// =====================================================================
// winattn8b = winattn8 (verified 68us: m/n-swapped GEMM, swizzled
// tiles, T14 staging, cvt_pk, bounds(256,4), LDS 36864) with the O
// write changed: both heads' O held in regs, staged bf16 through the
// dead wave-private Pb rows, then 16B coalesced stores into ws O
// (bf16, token-major) instead of f32 d_out. grid 4096, 256 thr.
// =====================================================================
__global__ __launch_bounds__(256, 4)
void winattn8b(const float* __restrict__ x,
               const unsigned short* __restrict__ wqkvT,
               const float* __restrict__ bias_tab,
               unsigned short* __restrict__ wsO)
{
    __shared__ __align__(16) unsigned char smem[36864];
    typedef unsigned short (*arr40)[40];
    // GEMM-phase views (swizzled 128B rows)
    unsigned char* Xb = smem;                               // [64][128B]
    unsigned char* Wb = smem + 8192;                        // [192][128B]
    // attn-phase views (alias; valid after post-GEMM barrier)
    arr40 sQ = reinterpret_cast<arr40>(smem);               // [128][40]
    arr40 sK = reinterpret_cast<arr40>(smem + 10240);       // [128][40]
    unsigned char* Vb = smem + 20480;                       // [64][128B] swz
    unsigned char* Pb = smem + 28672;                       // [64][128B] swz

    const int tid  = threadIdx.x;
    const int lane = tid & 63;
    const int wv   = tid >> 6;
    const int ln   = lane & 15;
    const int lg   = lane >> 4;

    // XCD swizzle: the 4 blocks of one window land on the same XCD
    const int L   = ((blockIdx.x & 7) << 9) + (blockIdx.x >> 3);
    const int wid = L >> 2;
    const int h0  = (L & 3) << 1;          // head pair h0, h0+1
    const int blw = wid >> 6;
    const int whr = (wid >> 3) & 7;
    const int wwc = wid & 7;
    const int tok_base = blw * 4096 + whr * 512 + wwc * 8;
    // token(i) = tok_base + (i>>3)*64 + (i&7)

    // ---- staging thread maps (T14 async-split, verified rounds 9-12) ----
    const int c8    = tid & 7;             // 16B slot within row
    const int xrow0 = tid >> 3;            // X rows 0..31
    const int xrow1 = 32 + (tid >> 3);     //        32..63
    const float* xs0 = x + (size_t)(tok_base + ((xrow0 >> 3) << 6) + (xrow0 & 7)) * 256 + c8 * 8;
    const float* xs1 = x + (size_t)(tok_base + ((xrow1 >> 3) << 6) + (xrow1 & 7)) * 256 + c8 * 8;
    const int wrb = tid >> 3;
    const unsigned short* ws0; const unsigned short* ws1;
    const unsigned short* ws2; const unsigned short* ws3;
    const unsigned short* ws4; const unsigned short* ws5;
    {
        #define WSRC(IT) ({ int r = (IT)*32 + wrb; int nt_ = r >> 4;          \
            int m_ = nt_ >> 2, hp_ = (nt_ >> 1) & 1, hf_ = nt_ & 1;           \
            int n = m_ * 256 + (h0 + hp_) * 32 + hf_ * 16 + (r & 15);         \
            wqkvT + (size_t)n * 256 + c8 * 8; })
        ws0 = WSRC(0); ws1 = WSRC(1); ws2 = WSRC(2);
        ws3 = WSRC(3); ws4 = WSRC(4); ws5 = WSRC(5);
        #undef WSRC
    }

    // ---- prologue: load chunk 0 into registers ----
    float4 xa0 = *reinterpret_cast<const float4*>(xs0);
    float4 xb0 = *reinterpret_cast<const float4*>(xs0 + 4);
    float4 xa1 = *reinterpret_cast<const float4*>(xs1);
    float4 xb1 = *reinterpret_cast<const float4*>(xs1 + 4);
    bf16x8 w0 = *reinterpret_cast<const bf16x8*>(ws0);
    bf16x8 w1 = *reinterpret_cast<const bf16x8*>(ws1);
    bf16x8 w2 = *reinterpret_cast<const bf16x8*>(ws2);
    bf16x8 w3 = *reinterpret_cast<const bf16x8*>(ws3);
    bf16x8 w4 = *reinterpret_cast<const bf16x8*>(ws4);
    bf16x8 w5 = *reinterpret_cast<const bf16x8*>(ws5);

    f32x4 acc[4][3];
    #pragma unroll
    for (int mt = 0; mt < 4; ++mt)
        #pragma unroll
        for (int jt = 0; jt < 3; ++jt) acc[mt][jt] = (f32x4)(0.f);

    #pragma unroll
    for (int kc = 0; kc < 4; ++kc) {
        // ---- write phase: regs (chunk kc) -> swizzled LDS ----
        *reinterpret_cast<bf16x8*>(Xb + swz(xrow0, c8 * 16)) = cvt8(xa0, xb0);
        *reinterpret_cast<bf16x8*>(Xb + swz(xrow1, c8 * 16)) = cvt8(xa1, xb1);
        *reinterpret_cast<bf16x8*>(Wb + swz(0 * 32 + wrb, c8 * 16)) = w0;
        *reinterpret_cast<bf16x8*>(Wb + swz(1 * 32 + wrb, c8 * 16)) = w1;
        *reinterpret_cast<bf16x8*>(Wb + swz(2 * 32 + wrb, c8 * 16)) = w2;
        *reinterpret_cast<bf16x8*>(Wb + swz(3 * 32 + wrb, c8 * 16)) = w3;
        *reinterpret_cast<bf16x8*>(Wb + swz(4 * 32 + wrb, c8 * 16)) = w4;
        *reinterpret_cast<bf16x8*>(Wb + swz(5 * 32 + wrb, c8 * 16)) = w5;
        __syncthreads();                    // (A) writes visible

        // ---- issue chunk kc+1 loads (fly under the MFMAs below) ----
        if (kc < 3) {
            const int ko = (kc + 1) * 64;
            xa0 = *reinterpret_cast<const float4*>(xs0 + ko);
            xb0 = *reinterpret_cast<const float4*>(xs0 + ko + 4);
            xa1 = *reinterpret_cast<const float4*>(xs1 + ko);
            xb1 = *reinterpret_cast<const float4*>(xs1 + ko + 4);
            w0 = *reinterpret_cast<const bf16x8*>(ws0 + ko);
            w1 = *reinterpret_cast<const bf16x8*>(ws1 + ko);
            w2 = *reinterpret_cast<const bf16x8*>(ws2 + ko);
            w3 = *reinterpret_cast<const bf16x8*>(ws3 + ko);
            w4 = *reinterpret_cast<const bf16x8*>(ws4 + ko);
            w5 = *reinterpret_cast<const bf16x8*>(ws5 + ko);
        }

        // ---- MFMA phase: wave owns all 4 m-tiles x its 3 n-tiles ----
        #pragma unroll
        for (int ks = 0; ks < 2; ++ks) {
            const int cb = ks * 64 + lg * 16;   // byte col within row
            bf16x8 a0 = *reinterpret_cast<const bf16x8*>(Xb + swz(     ln, cb));
            bf16x8 a1 = *reinterpret_cast<const bf16x8*>(Xb + swz(16 + ln, cb));
            bf16x8 a2 = *reinterpret_cast<const bf16x8*>(Xb + swz(32 + ln, cb));
            bf16x8 a3 = *reinterpret_cast<const bf16x8*>(Xb + swz(48 + ln, cb));
            #pragma unroll
            for (int jt = 0; jt < 3; ++jt) {
                bf16x8 bb = *reinterpret_cast<const bf16x8*>(
                    Wb + swz((wv * 3 + jt) * 16 + ln, cb));
                acc[0][jt] = MFMA16(a0, bb, acc[0][jt], 0, 0, 0);
                acc[1][jt] = MFMA16(a1, bb, acc[1][jt], 0, 0, 0);
                acc[2][jt] = MFMA16(a2, bb, acc[2][jt], 0, 0, 0);
                acc[3][jt] = MFMA16(a3, bb, acc[3][jt], 0, 0, 0);
            }
        }
        __syncthreads();                    // (B) MFMA reads done
    }

    // ---- epilogue: per owned n-tile (wave-uniform branch) ----
    const float scale = 0.17677669529663687f;
    #pragma unroll
    for (int jt = 0; jt < 3; ++jt) {
        const int n_t = wv * 3 + jt;
        const int m  = n_t >> 2;
        const int hp = (n_t >> 1) & 1;
        const int hf = n_t & 1;
        if (m == 0) {          // Q (pre-scaled), [tok][ch] b16 scatter
            #pragma unroll
            for (int mt = 0; mt < 4; ++mt)
                #pragma unroll
                for (int r = 0; r < 4; ++r)
                    sQ[hp * 64 + mt * 16 + lg * 4 + r][hf * 16 + ln] =
                        f2bf(acc[mt][jt][r] * scale);
        } else if (m == 1) {   // K, [tok][ch] b16 scatter
            #pragma unroll
            for (int mt = 0; mt < 4; ++mt)
                #pragma unroll
                for (int r = 0; r < 4; ++r)
                    sK[hp * 64 + mt * 16 + lg * 4 + r][hf * 16 + ln] =
                        f2bf(acc[mt][jt][r]);
        } else {               // V -> VT[ch][tok], swizzled 8B packs
            const int row = hp * 32 + hf * 16 + ln;
            #pragma unroll
            for (int mt = 0; mt < 4; ++mt)
                *reinterpret_cast<uint2*>(Vb + swz(row, mt * 32 + lg * 8)) =
                    pk4(acc[mt][jt][0], acc[mt][jt][1],
                        acc[mt][jt][2], acc[mt][jt][3]);
        }
    }
    __syncthreads();

    // ---- attention: wave wv owns q-rows 16wv..16wv+15, both heads ----
    const int q = wv * 16 + ln;
    const int prow = wv * 16 + ln;
    float o0[2][4];                          // hp=0 O held in regs
    #pragma unroll
    for (int hp = 0; hp < 2; ++hp) {
        bf16x8 qf = *reinterpret_cast<const bf16x8*>(&sQ[hp * 64 + q][lg * 8]);
        f32x4 st[4];
        #pragma unroll
        for (int mt = 0; mt < 4; ++mt) {
            bf16x8 kf = *reinterpret_cast<const bf16x8*>(
                &sK[hp * 64 + mt * 16 + ln][lg * 8]);
            st[mt] = MFMA16(kf, qf, (f32x4)(0.f), 0, 0, 0);
        }

        float sv[16];
        float mx = -3.0e38f;
        #pragma unroll
        for (int mt = 0; mt < 4; ++mt) {
            float4 bt = *reinterpret_cast<const float4*>(
                &bias_tab[q * 64 + mt * 16 + lg * 4]);
            float b4[4] = {bt.x, bt.y, bt.z, bt.w};
            #pragma unroll
            for (int r = 0; r < 4; ++r) {
                float s = st[mt][r] + b4[r];
                sv[mt * 4 + r] = s;
                mx = fmaxf(mx, s);
            }
        }
        mx = fmaxf(mx, __shfl_xor(mx, 16));
        mx = fmaxf(mx, __shfl_xor(mx, 32));
        float sum = 0.f;
        #pragma unroll
        for (int i = 0; i < 16; ++i) { sv[i] = __expf(sv[i] - mx); sum += sv[i]; }
        sum += __shfl_xor(sum, 16);
        sum += __shfl_xor(sum, 32);
        const float inv = 1.0f / sum;

        #pragma unroll
        for (int mt = 0; mt < 4; ++mt)
            *reinterpret_cast<uint2*>(Pb + swz(prow, mt * 32 + lg * 8)) =
                pk4(sv[mt * 4 + 0] * inv, sv[mt * 4 + 1] * inv,
                    sv[mt * 4 + 2] * inv, sv[mt * 4 + 3] * inv);

        f32x4 o[2] = {(f32x4)(0.f), (f32x4)(0.f)};
        #pragma unroll
        for (int ks = 0; ks < 2; ++ks) {
            bf16x8 pf = *reinterpret_cast<const bf16x8*>(
                Pb + swz(prow, ks * 64 + lg * 16));
            #pragma unroll
            for (int nt = 0; nt < 2; ++nt) {
                bf16x8 vf = *reinterpret_cast<const bf16x8*>(
                    Vb + swz(hp * 32 + nt * 16 + ln, ks * 64 + lg * 16));
                o[nt] = MFMA16(pf, vf, o[nt], 0, 0, 0);
            }
        }

        if (hp == 0) {
            #pragma unroll
            for (int nt = 0; nt < 2; ++nt)
                #pragma unroll
                for (int r = 0; r < 4; ++r) o0[nt][r] = o[nt][r];
        } else {
            // ---- O staging: both heads -> wave-private Pb rows (P dead) ----
            #pragma unroll
            for (int nt = 0; nt < 2; ++nt)
                #pragma unroll
                for (int r = 0; r < 4; ++r) {
                    int rloc = wv * 16 + lg * 4 + r;
                    *reinterpret_cast<unsigned short*>(
                        Pb + swz(rloc, 2 * (nt * 16 + ln))) = f2bf(o0[nt][r]);
                    *reinterpret_cast<unsigned short*>(
                        Pb + swz(rloc, 2 * (32 + nt * 16 + ln))) = f2bf(o[nt][r]);
                }
            // wave-private RAW (compiler inserts lgkmcnt); coalesced out
            #pragma unroll
            for (int ps = 0; ps < 2; ++ps) {
                int rloc = wv * 16 + ps * 8 + (lane >> 3);
                int slot = lane & 7;
                bf16x8 ov = *reinterpret_cast<const bf16x8*>(
                    Pb + swz(rloc, slot * 16));
                int qi  = ps * 8 + (lane >> 3) + wv * 16;
                int tok = tok_base + ((qi >> 3) << 6) + (qi & 7);
                *reinterpret_cast<bf16x8*>(
                    wsO + (size_t)tok * 256 + h0 * 32 + slot * 8) = ov;
            }
        }
    }
}

// =====================================================================
// proj5b: out = O(bf16, ws) @ w_out + b_out -> d_out f32 (write-once).
// A-stage is a straight bf16 copy (no cvt). grid 1024, 256 thr.
// =====================================================================
__global__ __launch_bounds__(256, 3)
void proj5b(const unsigned short* __restrict__ wsO,
            const unsigned short* __restrict__ woutT,
            const float* __restrict__ b_out,
            float* __restrict__ outp)
{
    __shared__ __align__(16) unsigned short sA[64][264];

    const int tid  = threadIdx.x;
    const int lane = tid & 63;
    const int wv   = tid >> 6;
    const int ln   = lane & 15;
    const int lg   = lane >> 4;
    const size_t m0 = (size_t)blockIdx.x * 64;

    const unsigned short* b0 = woutT + (size_t)((wv +  0) * 16 + ln) * 256 + lg * 8;
    const unsigned short* b1 = woutT + (size_t)((wv +  4) * 16 + ln) * 256 + lg * 8;
    const unsigned short* b2 = woutT + (size_t)((wv +  8) * 16 + ln) * 256 + lg * 8;
    const unsigned short* b3 = woutT + (size_t)((wv + 12) * 16 + ln) * 256 + lg * 8;
    bf16x8 bc0 = *reinterpret_cast<const bf16x8*>(b0);
    bf16x8 bc1 = *reinterpret_cast<const bf16x8*>(b1);
    bf16x8 bc2 = *reinterpret_cast<const bf16x8*>(b2);
    bf16x8 bc3 = *reinterpret_cast<const bf16x8*>(b3);

    // stage A: straight bf16 copy (64 rows x 512B)
    #pragma unroll
    for (int it = 0; it < 8; ++it) {
        int idx = tid + (it << 8);
        int row = idx >> 5, c8 = idx & 31;
        *reinterpret_cast<bf16x8*>(&sA[row][c8 * 8]) =
            *reinterpret_cast<const bf16x8*>(wsO + (m0 + row) * 256 + c8 * 8);
    }
    __syncthreads();

    f32x4 acc[4][4];
    #pragma unroll
    for (int m = 0; m < 4; ++m)
        #pragma unroll
        for (int j = 0; j < 4; ++j) acc[m][j] = (f32x4)(0.f);

    #pragma unroll
    for (int st = 0; st < 8; ++st) {
        const int ko = st * 32 + lg * 8;
        bf16x8 a0 = *reinterpret_cast<const bf16x8*>(&sA[     ln][ko]);
        bf16x8 a1 = *reinterpret_cast<const bf16x8*>(&sA[16 + ln][ko]);
        bf16x8 a2 = *reinterpret_cast<const bf16x8*>(&sA[32 + ln][ko]);
        bf16x8 a3 = *reinterpret_cast<const bf16x8*>(&sA[48 + ln][ko]);
        bf16x8 bn0 = bc0, bn1 = bc1, bn2 = bc2, bn3 = bc3;
        if (st < 7) {
            bn0 = *reinterpret_cast<const bf16x8*>(b0 + (st + 1) * 32);
            bn1 = *reinterpret_cast<const bf16x8*>(b1 + (st + 1) * 32);
            bn2 = *reinterpret_cast<const bf16x8*>(b2 + (st + 1) * 32);
            bn3 = *reinterpret_cast<const bf16x8*>(b3 + (st + 1) * 32);
        }
        acc[0][0] = MFMA16(a0, bc0, acc[0][0], 0, 0, 0);
        acc[1][0] = MFMA16(a1, bc0, acc[1][0], 0, 0, 0);
        acc[2][0] = MFMA16(a2, bc0, acc[2][0], 0, 0, 0);
        acc[3][0] = MFMA16(a3, bc0, acc[3][0], 0, 0, 0);
        acc[0][1] = MFMA16(a0, bc1, acc[0][1], 0, 0, 0);
        acc[1][1] = MFMA16(a1, bc1, acc[1][1], 0, 0, 0);
        acc[2][1] = MFMA16(a2, bc1, acc[2][1], 0, 0, 0);
        acc[3][1] = MFMA16(a3, bc1, acc[3][1], 0, 0, 0);
        acc[0][2] = MFMA16(a0, bc2, acc[0][2], 0, 0, 0);
        acc[1][2] = MFMA16(a1, bc2, acc[1][2], 0, 0, 0);
        acc[2][2] = MFMA16(a2, bc2, acc[2][2], 0, 0, 0);
        acc[3][2] = MFMA16(a3, bc2, acc[3][2], 0, 0, 0);
        acc[0][3] = MFMA16(a0, bc3, acc[0][3], 0, 0, 0);
        acc[1][3] = MFMA16(a1, bc3, acc[1][3], 0, 0, 0);
        acc[2][3] = MFMA16(a2, bc3, acc[2][3], 0, 0, 0);
        acc[3][3] = MFMA16(a3, bc3, acc[3][3], 0, 0, 0);
        bc0 = bn0; bc1 = bn1; bc2 = bn2; bc3 = bn3;
    }

    #pragma unroll
    for (int j = 0; j < 4; ++j) {
        int nt = wv + 4 * j;
        float bias = b_out[nt * 16 + ln];
        #pragma unroll
        for (int m = 0; m < 4; ++m)
            #pragma unroll
            for (int r = 0; r < 4; ++r)
                outp[(m0 + m * 16 + lg * 4 + r) * 256 + nt * 16 + ln] =
                    acc[m][j][r] + bias;
    }
}

// =====================================================================
// Fallback (round-3 verified kernels) if ws_size < WS_NEED2.
// =====================================================================
__device__ __forceinline__ bf16x8 ldsFrag(const unsigned short* p) {
    return *reinterpret_cast<const bf16x8*>(p);
}

__global__ __launch_bounds__(256, 2)
void winattn_fb(const float* __restrict__ x,
                const float* __restrict__ w_qkv,
                const float* __restrict__ pe,
                float* __restrict__ attn_out)
{
    __shared__ __align__(16) unsigned short sX[64][264];
    __shared__ __align__(16) unsigned short sW[96][72];
    __shared__ __align__(16) unsigned short sQ[64][40];
    __shared__ __align__(16) unsigned short sK[64][40];
    __shared__ __align__(16) unsigned short sVT[32][72];
    __shared__ float sPE[225];
    unsigned short* sP = &sX[0][0];

    const int tid  = threadIdx.x;
    const int lane = tid & 63;
    const int wv   = tid >> 6;
    const int ln   = lane & 15;
    const int lg   = lane >> 4;

    const int h   = blockIdx.x & 7;
    const int wid = blockIdx.x >> 3;
    const int blw = wid >> 6;
    const int whr = (wid >> 3) & 7;
    const int wwc = wid & 7;
    const int tok_base = blw * 4096 + whr * 512 + wwc * 8;

    if (tid < 225) sPE[tid] = pe[tid];

    #pragma unroll
    for (int it = 0; it < 16; ++it) {
        int g = tid + (it << 8);
        int row = g >> 6, f4 = g & 63;
        int tok = tok_base + ((row >> 3) << 6) + (row & 7);
        float4 v = *reinterpret_cast<const float4*>(x + (size_t)tok * 256 + f4 * 4);
        ushort4 u;
        u.x = f2bf(v.x); u.y = f2bf(v.y); u.z = f2bf(v.z); u.w = f2bf(v.w);
        *reinterpret_cast<ushort4*>(&sX[row][f4 << 2]) = u;
    }

    auto stage_w = [&](int kc) {
        #pragma unroll
        for (int it = 0; it < 8; ++it) {
            int g = tid + (it << 8);
            int k = g >> 5, c = g & 31;
            if (c < 24) {
                int m = c >> 3, f4 = c & 7;
                float4 v = *reinterpret_cast<const float4*>(
                    w_qkv + (size_t)(kc * 64 + k) * 768 + m * 256 + h * 32 + f4 * 4);
                float vals[4] = {v.x, v.y, v.z, v.w};
                int n0 = m * 32 + f4 * 4;
                #pragma unroll
                for (int e0 = 0; e0 < 4; ++e0) {
                    int e = (e0 + lane) & 3;
                    sW[n0 + e][k] = f2bf(vals[e]);
                }
            }
        }
    };

    stage_w(0);
    __syncthreads();

    f32x4 acc[6];
    #pragma unroll
    for (int nt = 0; nt < 6; ++nt) acc[nt] = (f32x4)(0.f);

    for (int kc = 0; kc < 4; ++kc) {
        #pragma unroll
        for (int ks = 0; ks < 2; ++ks) {
            bf16x8 a = ldsFrag(&sX[wv * 16 + ln][kc * 64 + ks * 32 + lg * 8]);
            #pragma unroll
            for (int nt = 0; nt < 6; ++nt) {
                bf16x8 b = ldsFrag(&sW[nt * 16 + ln][ks * 32 + lg * 8]);
                acc[nt] = MFMA16(a, b, acc[nt], 0, 0, 0);
            }
        }
        if (kc < 3) { __syncthreads(); stage_w(kc + 1); __syncthreads(); }
    }

    #pragma unroll
    for (int nt = 0; nt < 4; ++nt)
        #pragma unroll
        for (int r = 0; r < 4; ++r) {
            int row = wv * 16 + lg * 4 + r;
            unsigned short bv = f2bf(acc[nt][r]);
            if (nt < 2) sQ[row][nt * 16 + ln] = bv;
            else        sK[row][(nt - 2) * 16 + ln] = bv;
        }
    #pragma unroll
    for (int nt = 4; nt < 6; ++nt) {
        ushort4 pv;
        pv.x = f2bf(acc[nt][0]); pv.y = f2bf(acc[nt][1]);
        pv.z = f2bf(acc[nt][2]); pv.w = f2bf(acc[nt][3]);
        *reinterpret_cast<ushort4*>(&sVT[(nt - 4) * 16 + ln][wv * 16 + lg * 4]) = pv;
    }
    __syncthreads();

    const f32x4 zero = (f32x4)(0.f);
    bf16x8 qf = ldsFrag(&sQ[wv * 16 + ln][lg * 8]);
    f32x4 st[4];
    #pragma unroll
    for (int mt = 0; mt < 4; ++mt) {
        bf16x8 kf = ldsFrag(&sK[mt * 16 + ln][lg * 8]);
        st[mt] = MFMA16(kf, qf, zero, 0, 0, 0);
    }

    const int q = wv * 16 + ln;
    const int qr = q >> 3, qc = q & 7;
    const float scale = 0.17677669529663687f;
    float sv[16];
    float mx = -3.0e38f;
    #pragma unroll
    for (int mt = 0; mt < 4; ++mt)
        #pragma unroll
        for (int r = 0; r < 4; ++r) {
            int j = mt * 16 + lg * 4 + r;
            int dy = (j >> 3) - qr + 7;
            int dx = (j & 7) - qc + 7;
            float s = st[mt][r] * scale + sPE[dy * 15 + dx];
            sv[mt * 4 + r] = s;
            mx = fmaxf(mx, s);
        }
    mx = fmaxf(mx, __shfl_xor(mx, 16));
    mx = fmaxf(mx, __shfl_xor(mx, 32));
    float sum = 0.f;
    #pragma unroll
    for (int i = 0; i < 16; ++i) { sv[i] = __expf(sv[i] - mx); sum += sv[i]; }
    sum += __shfl_xor(sum, 16);
    sum += __shfl_xor(sum, 32);
    const float inv = 1.0f / sum;

    unsigned short* sPw = sP + wv * (16 * 72) + ln * 72;
    #pragma unroll
    for (int mt = 0; mt < 4; ++mt) {
        ushort4 pv;
        pv.x = f2bf(sv[mt * 4 + 0] * inv);
        pv.y = f2bf(sv[mt * 4 + 1] * inv);
        pv.z = f2bf(sv[mt * 4 + 2] * inv);
        pv.w = f2bf(sv[mt * 4 + 3] * inv);
        *reinterpret_cast<ushort4*>(sPw + mt * 16 + lg * 4) = pv;
    }

    f32x4 o[2] = {zero, zero};
    #pragma unroll
    for (int ks = 0; ks < 2; ++ks) {
        bf16x8 pf = ldsFrag(sPw + ks * 32 + lg * 8);
        #pragma unroll
        for (int nt = 0; nt < 2; ++nt) {
            bf16x8 vf = ldsFrag(&sVT[nt * 16 + ln][ks * 32 + lg * 8]);
            o[nt] = MFMA16(pf, vf, o[nt], 0, 0, 0);
        }
    }
    #pragma unroll
    for (int nt = 0; nt < 2; ++nt)
        #pragma unroll
        for (int r = 0; r < 4; ++r) {
            int qi = wv * 16 + lg * 4 + r;
            int tok = tok_base + ((qi >> 3) << 6) + (qi & 7);
            attn_out[(size_t)tok * 256 + h * 32 + nt * 16 + ln] = o[nt][r];
        }
}

__global__ __launch_bounds__(256, 3)
void proj_fb(float* __restrict__ io,
             const float* __restrict__ w_out,
             const float* __restrict__ b_out)
{
    __shared__ __align__(16) unsigned short sA[64][72];
    __shared__ __align__(16) unsigned short sW2[256][72];
    __shared__ float sB[256];

    const int tid  = threadIdx.x;
    const int lane = tid & 63;
    const int wv   = tid >> 6;
    const int ln   = lane & 15;
    const int lg   = lane >> 4;
    const size_t m0 = (size_t)blockIdx.x * 64;

    sB[tid] = b_out[tid];

    f32x4 acc[16];
    #pragma unroll
    for (int nt = 0; nt < 16; ++nt) acc[nt] = (f32x4)(0.f);

    for (int kc = 0; kc < 4; ++kc) {
        if (kc) __syncthreads();
        #pragma unroll
        for (int it = 0; it < 4; ++it) {
            int g = tid + (it << 8);
            int row = g >> 4, f4 = g & 15;
            float4 v = *reinterpret_cast<const float4*>(
                io + (m0 + row) * 256 + kc * 64 + f4 * 4);
            ushort4 u;
            u.x = f2bf(v.x); u.y = f2bf(v.y); u.z = f2bf(v.z); u.w = f2bf(v.w);
            *reinterpret_cast<ushort4*>(&sA[row][f4 << 2]) = u;
        }
        #pragma unroll
        for (int i = 0; i < 16; ++i) {
            int f4 = ln + 16 * (i & 3);
            int kl = 16 * wv + lg + 4 * (i >> 2);
            float4 v = *reinterpret_cast<const float4*>(
                w_out + (size_t)(kc * 64 + kl) * 256 + f4 * 4);
            float vals[4] = {v.x, v.y, v.z, v.w};
            #pragma unroll
            for (int e0 = 0; e0 < 4; ++e0) {
                int e = (e0 + lane) & 3;
                sW2[f4 * 4 + e][kl] = f2bf(vals[e]);
            }
        }
        __syncthreads();

        #pragma unroll
        for (int ks = 0; ks < 2; ++ks) {
            bf16x8 a = ldsFrag(&sA[wv * 16 + ln][ks * 32 + lg * 8]);
            #pragma unroll
            for (int nt = 0; nt < 16; ++nt) {
                bf16x8 b = ldsFrag(&sW2[nt * 16 + ln][ks * 32 + lg * 8]);
                acc[nt] = MFMA16(a, b, acc[nt], 0, 0, 0);
            }
        }
    }

    #pragma unroll
    for (int nt = 0; nt < 16; ++nt) {
        float bias = sB[nt * 16 + ln];
        #pragma unroll
        for (int r = 0; r < 4; ++r) {
            int row = wv * 16 + lg * 4 + r;
            io[(m0 + row) * 256 + nt * 16 + ln] = acc[nt][r] + bias;
        }
    }
}

extern "C" void kernel_launch(void* const* d_in, const int* in_sizes, int n_in,
                              void* d_out, int out_size, void* d_ws, size_t ws_size,
                              hipStream_t stream) {
    const float* x     = (const float*)d_in[0];
    const float* w_qkv = (const float*)d_in[1];
    const float* w_out = (const float*)d_in[2];
    const float* b_out = (const float*)d_in[3];
    const float* pe    = (const float*)d_in[4];
    (void)in_sizes; (void)n_in; (void)out_size;

    float* out = (float*)d_out;

    if (ws_size >= (size_t)WS_NEED2) {
        unsigned short* wsT = (unsigned short*)d_ws;
        float* bias_tab = (float*)((char*)d_ws + 524288);
        unsigned short* wsO = wsT + O_SHORT_OFF;
        prep_kernel<<<dim3(257),  dim3(256), 0, stream>>>(w_qkv, w_out, pe, wsT, bias_tab);
        winattn8b  <<<dim3(4096), dim3(256), 0, stream>>>(x, wsT, bias_tab, wsO);
        proj5b     <<<dim3(1024), dim3(256), 0, stream>>>(wsO, wsT + WOUTT_SHORT_OFF, b_out, out);
    } else {
        winattn_fb <<<dim3(8192), dim3(256), 0, stream>>>(x, w_qkv, pe, out);
        proj_fb    <<<dim3(1024), dim3(256), 0, stream>>>(out, w_out, b_out);
    }
}

// Round 15
// 85.846 us; speedup vs baseline: 1.1165x; 1.0041x over previous
//
#include <hip/hip_runtime.h>

typedef float f32x4 __attribute__((ext_vector_type(4)));
typedef short bf16x8 __attribute__((ext_vector_type(8)));

#define MFMA16 __builtin_amdgcn_mfma_f32_16x16x32_bf16

// ---------- bf16 conversion via HW packed cvt (RNE, 1 op / 2 values) ----------
__device__ __forceinline__ unsigned int cvtpk(float lo, float hi) {
    unsigned int r;
    asm("v_cvt_pk_bf16_f32 %0, %1, %2" : "=v"(r) : "v"(lo), "v"(hi));
    return r;
}
__device__ __forceinline__ unsigned short f2bf(float f) {
    return (unsigned short)cvtpk(f, f);
}
__device__ __forceinline__ bf16x8 cvt8(float4 a, float4 b) {
    union { bf16x8 v; unsigned int u[4]; } r;
    r.u[0] = cvtpk(a.x, a.y); r.u[1] = cvtpk(a.z, a.w);
    r.u[2] = cvtpk(b.x, b.y); r.u[3] = cvtpk(b.z, b.w);
    return r.v;
}
__device__ __forceinline__ uint2 pk4(float a, float b, float c, float d) {
    return make_uint2(cvtpk(a, b), cvtpk(c, d));
}
// XOR-16B-slot swizzle for 128B-row tiles (write & read use the same map)
__device__ __forceinline__ int swz(int row, int byteoff) {
    return row * 128 + ((((byteoff >> 4) ^ (row & 7)) << 4) | (byteoff & 15));
}

// ws layout (bytes):
//   0        : WqkvT bf16 [768][256]   (393216 B)
//   393216   : WoutT bf16 [256][256]   (131072 B)
//   524288   : bias_tab f32 [64][64]   (16384 B)
//   540672   : O bf16 [65536][256]     (33554432 B)  token-major attn out
#define WS_NEED   540672
#define WS_NEED2  34095104
#define WOUTT_SHORT_OFF 196608
#define O_SHORT_OFF     270336

// =====================================================================
// Prep: transpose weights to bf16 n-major; expand PE to [q][j] table.
// =====================================================================
__global__ void prep_kernel(const float* __restrict__ wqkv,
                            const float* __restrict__ wout,
                            const float* __restrict__ pe,
                            unsigned short* __restrict__ wsT,
                            float* __restrict__ bias_tab)
{
    const int b = blockIdx.x, tid = threadIdx.x;
    if (b < 256) {
        const int w = tid >> 6, l = tid & 63;
        const int r = b * 4 + w;               // output row (n)
        const float* src;
        unsigned short* dst;
        int stride;
        if (r < 768) { src = wqkv + r; stride = 768; dst = wsT + (size_t)r * 256; }
        else { int n = r - 768; src = wout + n; stride = 256;
               dst = wsT + WOUTT_SHORT_OFF + (size_t)n * 256; }
        ushort4 v;
        v.x = f2bf(src[(size_t)(l * 4 + 0) * stride]);
        v.y = f2bf(src[(size_t)(l * 4 + 1) * stride]);
        v.z = f2bf(src[(size_t)(l * 4 + 2) * stride]);
        v.w = f2bf(src[(size_t)(l * 4 + 3) * stride]);
        *reinterpret_cast<ushort4*>(dst + l * 4) = v;
    } else {
        #pragma unroll
        for (int i = 0; i < 16; ++i) {
            int idx = tid + i * 256;           // q*64 + j
            int q = idx >> 6, j = idx & 63;
            int dy = (j >> 3) - (q >> 3) + 7;
            int dx = (j & 7) - (q & 7) + 7;
            bias_tab[idx] = pe[dy * 15 + dx];
        }
    }
}

// =====================================================================
// winattn8b = winattn8 (verified 68us: m/n-swapped GEMM, swizzled
// tiles, T14 staging, cvt_pk, bounds(256,4), LDS 36864) with the O
// write changed: both heads' O held in regs, staged bf16 through the
// dead wave-private Pb rows, then 16B coalesced stores into ws O
// (bf16, token-major) instead of f32 d_out. grid 4096, 256 thr.
// =====================================================================
__global__ __launch_bounds__(256, 4)
void winattn8b(const float* __restrict__ x,
               const unsigned short* __restrict__ wqkvT,
               const float* __restrict__ bias_tab,
               unsigned short* __restrict__ wsO)
{
    __shared__ __align__(16) unsigned char smem[36864];
    typedef unsigned short (*arr40)[40];
    // GEMM-phase views (swizzled 128B rows)
    unsigned char* Xb = smem;                               // [64][128B]
    unsigned char* Wb = smem + 8192;                        // [192][128B]
    // attn-phase views (alias; valid after post-GEMM barrier)
    arr40 sQ = reinterpret_cast<arr40>(smem);               // [128][40]
    arr40 sK = reinterpret_cast<arr40>(smem + 10240);       // [128][40]
    unsigned char* Vb = smem + 20480;                       // [64][128B] swz
    unsigned char* Pb = smem + 28672;                       // [64][128B] swz

    const int tid  = threadIdx.x;
    const int lane = tid & 63;
    const int wv   = tid >> 6;
    const int ln   = lane & 15;
    const int lg   = lane >> 4;

    // XCD swizzle: the 4 blocks of one window land on the same XCD
    const int L   = ((blockIdx.x & 7) << 9) + (blockIdx.x >> 3);
    const int wid = L >> 2;
    const int h0  = (L & 3) << 1;          // head pair h0, h0+1
    const int blw = wid >> 6;
    const int whr = (wid >> 3) & 7;
    const int wwc = wid & 7;
    const int tok_base = blw * 4096 + whr * 512 + wwc * 8;
    // token(i) = tok_base + (i>>3)*64 + (i&7)

    // ---- staging thread maps (T14 async-split, verified rounds 9-12) ----
    const int c8    = tid & 7;             // 16B slot within row
    const int xrow0 = tid >> 3;            // X rows 0..31
    const int xrow1 = 32 + (tid >> 3);     //        32..63
    const float* xs0 = x + (size_t)(tok_base + ((xrow0 >> 3) << 6) + (xrow0 & 7)) * 256 + c8 * 8;
    const float* xs1 = x + (size_t)(tok_base + ((xrow1 >> 3) << 6) + (xrow1 & 7)) * 256 + c8 * 8;
    const int wrb = tid >> 3;
    const unsigned short* ws0; const unsigned short* ws1;
    const unsigned short* ws2; const unsigned short* ws3;
    const unsigned short* ws4; const unsigned short* ws5;
    {
        #define WSRC(IT) ({ int r = (IT)*32 + wrb; int nt_ = r >> 4;          \
            int m_ = nt_ >> 2, hp_ = (nt_ >> 1) & 1, hf_ = nt_ & 1;           \
            int n = m_ * 256 + (h0 + hp_) * 32 + hf_ * 16 + (r & 15);         \
            wqkvT + (size_t)n * 256 + c8 * 8; })
        ws0 = WSRC(0); ws1 = WSRC(1); ws2 = WSRC(2);
        ws3 = WSRC(3); ws4 = WSRC(4); ws5 = WSRC(5);
        #undef WSRC
    }

    // ---- prologue: load chunk 0 into registers ----
    float4 xa0 = *reinterpret_cast<const float4*>(xs0);
    float4 xb0 = *reinterpret_cast<const float4*>(xs0 + 4);
    float4 xa1 = *reinterpret_cast<const float4*>(xs1);
    float4 xb1 = *reinterpret_cast<const float4*>(xs1 + 4);
    bf16x8 w0 = *reinterpret_cast<const bf16x8*>(ws0);
    bf16x8 w1 = *reinterpret_cast<const bf16x8*>(ws1);
    bf16x8 w2 = *reinterpret_cast<const bf16x8*>(ws2);
    bf16x8 w3 = *reinterpret_cast<const bf16x8*>(ws3);
    bf16x8 w4 = *reinterpret_cast<const bf16x8*>(ws4);
    bf16x8 w5 = *reinterpret_cast<const bf16x8*>(ws5);

    f32x4 acc[4][3];
    #pragma unroll
    for (int mt = 0; mt < 4; ++mt)
        #pragma unroll
        for (int jt = 0; jt < 3; ++jt) acc[mt][jt] = (f32x4)(0.f);

    #pragma unroll
    for (int kc = 0; kc < 4; ++kc) {
        // ---- write phase: regs (chunk kc) -> swizzled LDS ----
        *reinterpret_cast<bf16x8*>(Xb + swz(xrow0, c8 * 16)) = cvt8(xa0, xb0);
        *reinterpret_cast<bf16x8*>(Xb + swz(xrow1, c8 * 16)) = cvt8(xa1, xb1);
        *reinterpret_cast<bf16x8*>(Wb + swz(0 * 32 + wrb, c8 * 16)) = w0;
        *reinterpret_cast<bf16x8*>(Wb + swz(1 * 32 + wrb, c8 * 16)) = w1;
        *reinterpret_cast<bf16x8*>(Wb + swz(2 * 32 + wrb, c8 * 16)) = w2;
        *reinterpret_cast<bf16x8*>(Wb + swz(3 * 32 + wrb, c8 * 16)) = w3;
        *reinterpret_cast<bf16x8*>(Wb + swz(4 * 32 + wrb, c8 * 16)) = w4;
        *reinterpret_cast<bf16x8*>(Wb + swz(5 * 32 + wrb, c8 * 16)) = w5;
        __syncthreads();                    // (A) writes visible

        // ---- issue chunk kc+1 loads (fly under the MFMAs below) ----
        if (kc < 3) {
            const int ko = (kc + 1) * 64;
            xa0 = *reinterpret_cast<const float4*>(xs0 + ko);
            xb0 = *reinterpret_cast<const float4*>(xs0 + ko + 4);
            xa1 = *reinterpret_cast<const float4*>(xs1 + ko);
            xb1 = *reinterpret_cast<const float4*>(xs1 + ko + 4);
            w0 = *reinterpret_cast<const bf16x8*>(ws0 + ko);
            w1 = *reinterpret_cast<const bf16x8*>(ws1 + ko);
            w2 = *reinterpret_cast<const bf16x8*>(ws2 + ko);
            w3 = *reinterpret_cast<const bf16x8*>(ws3 + ko);
            w4 = *reinterpret_cast<const bf16x8*>(ws4 + ko);
            w5 = *reinterpret_cast<const bf16x8*>(ws5 + ko);
        }

        // ---- MFMA phase: wave owns all 4 m-tiles x its 3 n-tiles ----
        #pragma unroll
        for (int ks = 0; ks < 2; ++ks) {
            const int cb = ks * 64 + lg * 16;   // byte col within row
            bf16x8 a0 = *reinterpret_cast<const bf16x8*>(Xb + swz(     ln, cb));
            bf16x8 a1 = *reinterpret_cast<const bf16x8*>(Xb + swz(16 + ln, cb));
            bf16x8 a2 = *reinterpret_cast<const bf16x8*>(Xb + swz(32 + ln, cb));
            bf16x8 a3 = *reinterpret_cast<const bf16x8*>(Xb + swz(48 + ln, cb));
            #pragma unroll
            for (int jt = 0; jt < 3; ++jt) {
                bf16x8 bb = *reinterpret_cast<const bf16x8*>(
                    Wb + swz((wv * 3 + jt) * 16 + ln, cb));
                acc[0][jt] = MFMA16(a0, bb, acc[0][jt], 0, 0, 0);
                acc[1][jt] = MFMA16(a1, bb, acc[1][jt], 0, 0, 0);
                acc[2][jt] = MFMA16(a2, bb, acc[2][jt], 0, 0, 0);
                acc[3][jt] = MFMA16(a3, bb, acc[3][jt], 0, 0, 0);
            }
        }
        __syncthreads();                    // (B) MFMA reads done
    }

    // ---- epilogue: per owned n-tile (wave-uniform branch) ----
    const float scale = 0.17677669529663687f;
    #pragma unroll
    for (int jt = 0; jt < 3; ++jt) {
        const int n_t = wv * 3 + jt;
        const int m  = n_t >> 2;
        const int hp = (n_t >> 1) & 1;
        const int hf = n_t & 1;
        if (m == 0) {          // Q (pre-scaled), [tok][ch] b16 scatter
            #pragma unroll
            for (int mt = 0; mt < 4; ++mt)
                #pragma unroll
                for (int r = 0; r < 4; ++r)
                    sQ[hp * 64 + mt * 16 + lg * 4 + r][hf * 16 + ln] =
                        f2bf(acc[mt][jt][r] * scale);
        } else if (m == 1) {   // K, [tok][ch] b16 scatter
            #pragma unroll
            for (int mt = 0; mt < 4; ++mt)
                #pragma unroll
                for (int r = 0; r < 4; ++r)
                    sK[hp * 64 + mt * 16 + lg * 4 + r][hf * 16 + ln] =
                        f2bf(acc[mt][jt][r]);
        } else {               // V -> VT[ch][tok], swizzled 8B packs
            const int row = hp * 32 + hf * 16 + ln;
            #pragma unroll
            for (int mt = 0; mt < 4; ++mt)
                *reinterpret_cast<uint2*>(Vb + swz(row, mt * 32 + lg * 8)) =
                    pk4(acc[mt][jt][0], acc[mt][jt][1],
                        acc[mt][jt][2], acc[mt][jt][3]);
        }
    }
    __syncthreads();

    // ---- attention: wave wv owns q-rows 16wv..16wv+15, both heads ----
    const int q = wv * 16 + ln;
    const int prow = wv * 16 + ln;
    float o0[2][4];                          // hp=0 O held in regs
    #pragma unroll
    for (int hp = 0; hp < 2; ++hp) {
        bf16x8 qf = *reinterpret_cast<const bf16x8*>(&sQ[hp * 64 + q][lg * 8]);
        f32x4 st[4];
        #pragma unroll
        for (int mt = 0; mt < 4; ++mt) {
            bf16x8 kf = *reinterpret_cast<const bf16x8*>(
                &sK[hp * 64 + mt * 16 + ln][lg * 8]);
            st[mt] = MFMA16(kf, qf, (f32x4)(0.f), 0, 0, 0);
        }

        float sv[16];
        float mx = -3.0e38f;
        #pragma unroll
        for (int mt = 0; mt < 4; ++mt) {
            float4 bt = *reinterpret_cast<const float4*>(
                &bias_tab[q * 64 + mt * 16 + lg * 4]);
            float b4[4] = {bt.x, bt.y, bt.z, bt.w};
            #pragma unroll
            for (int r = 0; r < 4; ++r) {
                float s = st[mt][r] + b4[r];
                sv[mt * 4 + r] = s;
                mx = fmaxf(mx, s);
            }
        }
        mx = fmaxf(mx, __shfl_xor(mx, 16));
        mx = fmaxf(mx, __shfl_xor(mx, 32));
        float sum = 0.f;
        #pragma unroll
        for (int i = 0; i < 16; ++i) { sv[i] = __expf(sv[i] - mx); sum += sv[i]; }
        sum += __shfl_xor(sum, 16);
        sum += __shfl_xor(sum, 32);
        const float inv = 1.0f / sum;

        #pragma unroll
        for (int mt = 0; mt < 4; ++mt)
            *reinterpret_cast<uint2*>(Pb + swz(prow, mt * 32 + lg * 8)) =
                pk4(sv[mt * 4 + 0] * inv, sv[mt * 4 + 1] * inv,
                    sv[mt * 4 + 2] * inv, sv[mt * 4 + 3] * inv);

        f32x4 o[2] = {(f32x4)(0.f), (f32x4)(0.f)};
        #pragma unroll
        for (int ks = 0; ks < 2; ++ks) {
            bf16x8 pf = *reinterpret_cast<const bf16x8*>(
                Pb + swz(prow, ks * 64 + lg * 16));
            #pragma unroll
            for (int nt = 0; nt < 2; ++nt) {
                bf16x8 vf = *reinterpret_cast<const bf16x8*>(
                    Vb + swz(hp * 32 + nt * 16 + ln, ks * 64 + lg * 16));
                o[nt] = MFMA16(pf, vf, o[nt], 0, 0, 0);
            }
        }

        if (hp == 0) {
            #pragma unroll
            for (int nt = 0; nt < 2; ++nt)
                #pragma unroll
                for (int r = 0; r < 4; ++r) o0[nt][r] = o[nt][r];
        } else {
            // ---- O staging: both heads -> wave-private Pb rows (P dead) ----
            #pragma unroll
            for (int nt = 0; nt < 2; ++nt)
                #pragma unroll
                for (int r = 0; r < 4; ++r) {
                    int rloc = wv * 16 + lg * 4 + r;
                    *reinterpret_cast<unsigned short*>(
                        Pb + swz(rloc, 2 * (nt * 16 + ln))) = f2bf(o0[nt][r]);
                    *reinterpret_cast<unsigned short*>(
                        Pb + swz(rloc, 2 * (32 + nt * 16 + ln))) = f2bf(o[nt][r]);
                }
            // wave-private RAW (compiler inserts lgkmcnt); coalesced out
            #pragma unroll
            for (int ps = 0; ps < 2; ++ps) {
                int rloc = wv * 16 + ps * 8 + (lane >> 3);
                int slot = lane & 7;
                bf16x8 ov = *reinterpret_cast<const bf16x8*>(
                    Pb + swz(rloc, slot * 16));
                int qi  = ps * 8 + (lane >> 3) + wv * 16;
                int tok = tok_base + ((qi >> 3) << 6) + (qi & 7);
                *reinterpret_cast<bf16x8*>(
                    wsO + (size_t)tok * 256 + h0 * 32 + slot * 8) = ov;
            }
        }
    }
}

// =====================================================================
// proj5b: out = O(bf16, ws) @ w_out + b_out -> d_out f32 (write-once).
// A-stage is a straight bf16 copy (no cvt). grid 1024, 256 thr.
// =====================================================================
__global__ __launch_bounds__(256, 3)
void proj5b(const unsigned short* __restrict__ wsO,
            const unsigned short* __restrict__ woutT,
            const float* __restrict__ b_out,
            float* __restrict__ outp)
{
    __shared__ __align__(16) unsigned short sA[64][264];

    const int tid  = threadIdx.x;
    const int lane = tid & 63;
    const int wv   = tid >> 6;
    const int ln   = lane & 15;
    const int lg   = lane >> 4;
    const size_t m0 = (size_t)blockIdx.x * 64;

    const unsigned short* b0 = woutT + (size_t)((wv +  0) * 16 + ln) * 256 + lg * 8;
    const unsigned short* b1 = woutT + (size_t)((wv +  4) * 16 + ln) * 256 + lg * 8;
    const unsigned short* b2 = woutT + (size_t)((wv +  8) * 16 + ln) * 256 + lg * 8;
    const unsigned short* b3 = woutT + (size_t)((wv + 12) * 16 + ln) * 256 + lg * 8;
    bf16x8 bc0 = *reinterpret_cast<const bf16x8*>(b0);
    bf16x8 bc1 = *reinterpret_cast<const bf16x8*>(b1);
    bf16x8 bc2 = *reinterpret_cast<const bf16x8*>(b2);
    bf16x8 bc3 = *reinterpret_cast<const bf16x8*>(b3);

    // stage A: straight bf16 copy (64 rows x 512B)
    #pragma unroll
    for (int it = 0; it < 8; ++it) {
        int idx = tid + (it << 8);
        int row = idx >> 5, c8 = idx & 31;
        *reinterpret_cast<bf16x8*>(&sA[row][c8 * 8]) =
            *reinterpret_cast<const bf16x8*>(wsO + (m0 + row) * 256 + c8 * 8);
    }
    __syncthreads();

    f32x4 acc[4][4];
    #pragma unroll
    for (int m = 0; m < 4; ++m)
        #pragma unroll
        for (int j = 0; j < 4; ++j) acc[m][j] = (f32x4)(0.f);

    #pragma unroll
    for (int st = 0; st < 8; ++st) {
        const int ko = st * 32 + lg * 8;
        bf16x8 a0 = *reinterpret_cast<const bf16x8*>(&sA[     ln][ko]);
        bf16x8 a1 = *reinterpret_cast<const bf16x8*>(&sA[16 + ln][ko]);
        bf16x8 a2 = *reinterpret_cast<const bf16x8*>(&sA[32 + ln][ko]);
        bf16x8 a3 = *reinterpret_cast<const bf16x8*>(&sA[48 + ln][ko]);
        bf16x8 bn0 = bc0, bn1 = bc1, bn2 = bc2, bn3 = bc3;
        if (st < 7) {
            bn0 = *reinterpret_cast<const bf16x8*>(b0 + (st + 1) * 32);
            bn1 = *reinterpret_cast<const bf16x8*>(b1 + (st + 1) * 32);
            bn2 = *reinterpret_cast<const bf16x8*>(b2 + (st + 1) * 32);
            bn3 = *reinterpret_cast<const bf16x8*>(b3 + (st + 1) * 32);
        }
        acc[0][0] = MFMA16(a0, bc0, acc[0][0], 0, 0, 0);
        acc[1][0] = MFMA16(a1, bc0, acc[1][0], 0, 0, 0);
        acc[2][0] = MFMA16(a2, bc0, acc[2][0], 0, 0, 0);
        acc[3][0] = MFMA16(a3, bc0, acc[3][0], 0, 0, 0);
        acc[0][1] = MFMA16(a0, bc1, acc[0][1], 0, 0, 0);
        acc[1][1] = MFMA16(a1, bc1, acc[1][1], 0, 0, 0);
        acc[2][1] = MFMA16(a2, bc1, acc[2][1], 0, 0, 0);
        acc[3][1] = MFMA16(a3, bc1, acc[3][1], 0, 0, 0);
        acc[0][2] = MFMA16(a0, bc2, acc[0][2], 0, 0, 0);
        acc[1][2] = MFMA16(a1, bc2, acc[1][2], 0, 0, 0);
        acc[2][2] = MFMA16(a2, bc2, acc[2][2], 0, 0, 0);
        acc[3][2] = MFMA16(a3, bc2, acc[3][2], 0, 0, 0);
        acc[0][3] = MFMA16(a0, bc3, acc[0][3], 0, 0, 0);
        acc[1][3] = MFMA16(a1, bc3, acc[1][3], 0, 0, 0);
        acc[2][3] = MFMA16(a2, bc3, acc[2][3], 0, 0, 0);
        acc[3][3] = MFMA16(a3, bc3, acc[3][3], 0, 0, 0);
        bc0 = bn0; bc1 = bn1; bc2 = bn2; bc3 = bn3;
    }

    #pragma unroll
    for (int j = 0; j < 4; ++j) {
        int nt = wv + 4 * j;
        float bias = b_out[nt * 16 + ln];
        #pragma unroll
        for (int m = 0; m < 4; ++m)
            #pragma unroll
            for (int r = 0; r < 4; ++r)
                outp[(m0 + m * 16 + lg * 4 + r) * 256 + nt * 16 + ln] =
                    acc[m][j][r] + bias;
    }
}

// =====================================================================
// Fallback (round-3 verified kernels) if ws_size < WS_NEED2.
// =====================================================================
__device__ __forceinline__ bf16x8 ldsFrag(const unsigned short* p) {
    return *reinterpret_cast<const bf16x8*>(p);
}

__global__ __launch_bounds__(256, 2)
void winattn_fb(const float* __restrict__ x,
                const float* __restrict__ w_qkv,
                const float* __restrict__ pe,
                float* __restrict__ attn_out)
{
    __shared__ __align__(16) unsigned short sX[64][264];
    __shared__ __align__(16) unsigned short sW[96][72];
    __shared__ __align__(16) unsigned short sQ[64][40];
    __shared__ __align__(16) unsigned short sK[64][40];
    __shared__ __align__(16) unsigned short sVT[32][72];
    __shared__ float sPE[225];
    unsigned short* sP = &sX[0][0];

    const int tid  = threadIdx.x;
    const int lane = tid & 63;
    const int wv   = tid >> 6;
    const int ln   = lane & 15;
    const int lg   = lane >> 4;

    const int h   = blockIdx.x & 7;
    const int wid = blockIdx.x >> 3;
    const int blw = wid >> 6;
    const int whr = (wid >> 3) & 7;
    const int wwc = wid & 7;
    const int tok_base = blw * 4096 + whr * 512 + wwc * 8;

    if (tid < 225) sPE[tid] = pe[tid];

    #pragma unroll
    for (int it = 0; it < 16; ++it) {
        int g = tid + (it << 8);
        int row = g >> 6, f4 = g & 63;
        int tok = tok_base + ((row >> 3) << 6) + (row & 7);
        float4 v = *reinterpret_cast<const float4*>(x + (size_t)tok * 256 + f4 * 4);
        ushort4 u;
        u.x = f2bf(v.x); u.y = f2bf(v.y); u.z = f2bf(v.z); u.w = f2bf(v.w);
        *reinterpret_cast<ushort4*>(&sX[row][f4 << 2]) = u;
    }

    auto stage_w = [&](int kc) {
        #pragma unroll
        for (int it = 0; it < 8; ++it) {
            int g = tid + (it << 8);
            int k = g >> 5, c = g & 31;
            if (c < 24) {
                int m = c >> 3, f4 = c & 7;
                float4 v = *reinterpret_cast<const float4*>(
                    w_qkv + (size_t)(kc * 64 + k) * 768 + m * 256 + h * 32 + f4 * 4);
                float vals[4] = {v.x, v.y, v.z, v.w};
                int n0 = m * 32 + f4 * 4;
                #pragma unroll
                for (int e0 = 0; e0 < 4; ++e0) {
                    int e = (e0 + lane) & 3;
                    sW[n0 + e][k] = f2bf(vals[e]);
                }
            }
        }
    };

    stage_w(0);
    __syncthreads();

    f32x4 acc[6];
    #pragma unroll
    for (int nt = 0; nt < 6; ++nt) acc[nt] = (f32x4)(0.f);

    for (int kc = 0; kc < 4; ++kc) {
        #pragma unroll
        for (int ks = 0; ks < 2; ++ks) {
            bf16x8 a = ldsFrag(&sX[wv * 16 + ln][kc * 64 + ks * 32 + lg * 8]);
            #pragma unroll
            for (int nt = 0; nt < 6; ++nt) {
                bf16x8 b = ldsFrag(&sW[nt * 16 + ln][ks * 32 + lg * 8]);
                acc[nt] = MFMA16(a, b, acc[nt], 0, 0, 0);
            }
        }
        if (kc < 3) { __syncthreads(); stage_w(kc + 1); __syncthreads(); }
    }

    #pragma unroll
    for (int nt = 0; nt < 4; ++nt)
        #pragma unroll
        for (int r = 0; r < 4; ++r) {
            int row = wv * 16 + lg * 4 + r;
            unsigned short bv = f2bf(acc[nt][r]);
            if (nt < 2) sQ[row][nt * 16 + ln] = bv;
            else        sK[row][(nt - 2) * 16 + ln] = bv;
        }
    #pragma unroll
    for (int nt = 4; nt < 6; ++nt) {
        ushort4 pv;
        pv.x = f2bf(acc[nt][0]); pv.y = f2bf(acc[nt][1]);
        pv.z = f2bf(acc[nt][2]); pv.w = f2bf(acc[nt][3]);
        *reinterpret_cast<ushort4*>(&sVT[(nt - 4) * 16 + ln][wv * 16 + lg * 4]) = pv;
    }
    __syncthreads();

    const f32x4 zero = (f32x4)(0.f);
    bf16x8 qf = ldsFrag(&sQ[wv * 16 + ln][lg * 8]);
    f32x4 st[4];
    #pragma unroll
    for (int mt = 0; mt < 4; ++mt) {
        bf16x8 kf = ldsFrag(&sK[mt * 16 + ln][lg * 8]);
        st[mt] = MFMA16(kf, qf, zero, 0, 0, 0);
    }

    const int q = wv * 16 + ln;
    const int qr = q >> 3, qc = q & 7;
    const float scale = 0.17677669529663687f;
    float sv[16];
    float mx = -3.0e38f;
    #pragma unroll
    for (int mt = 0; mt < 4; ++mt)
        #pragma unroll
        for (int r = 0; r < 4; ++r) {
            int j = mt * 16 + lg * 4 + r;
            int dy = (j >> 3) - qr + 7;
            int dx = (j & 7) - qc + 7;
            float s = st[mt][r] * scale + sPE[dy * 15 + dx];
            sv[mt * 4 + r] = s;
            mx = fmaxf(mx, s);
        }
    mx = fmaxf(mx, __shfl_xor(mx, 16));
    mx = fmaxf(mx, __shfl_xor(mx, 32));
    float sum = 0.f;
    #pragma unroll
    for (int i = 0; i < 16; ++i) { sv[i] = __expf(sv[i] - mx); sum += sv[i]; }
    sum += __shfl_xor(sum, 16);
    sum += __shfl_xor(sum, 32);
    const float inv = 1.0f / sum;

    unsigned short* sPw = sP + wv * (16 * 72) + ln * 72;
    #pragma unroll
    for (int mt = 0; mt < 4; ++mt) {
        ushort4 pv;
        pv.x = f2bf(sv[mt * 4 + 0] * inv);
        pv.y = f2bf(sv[mt * 4 + 1] * inv);
        pv.z = f2bf(sv[mt * 4 + 2] * inv);
        pv.w = f2bf(sv[mt * 4 + 3] * inv);
        *reinterpret_cast<ushort4*>(sPw + mt * 16 + lg * 4) = pv;
    }

    f32x4 o[2] = {zero, zero};
    #pragma unroll
    for (int ks = 0; ks < 2; ++ks) {
        bf16x8 pf = ldsFrag(sPw + ks * 32 + lg * 8);
        #pragma unroll
        for (int nt = 0; nt < 2; ++nt) {
            bf16x8 vf = ldsFrag(&sVT[nt * 16 + ln][ks * 32 + lg * 8]);
            o[nt] = MFMA16(pf, vf, o[nt], 0, 0, 0);
        }
    }
    #pragma unroll
    for (int nt = 0; nt < 2; ++nt)
        #pragma unroll
        for (int r = 0; r < 4; ++r) {
            int qi = wv * 16 + lg * 4 + r;
            int tok = tok_base + ((qi >> 3) << 6) + (qi & 7);
            attn_out[(size_t)tok * 256 + h * 32 + nt * 16 + ln] = o[nt][r];
        }
}

__global__ __launch_bounds__(256, 3)
void proj_fb(float* __restrict__ io,
             const float* __restrict__ w_out,
             const float* __restrict__ b_out)
{
    __shared__ __align__(16) unsigned short sA[64][72];
    __shared__ __align__(16) unsigned short sW2[256][72];
    __shared__ float sB[256];

    const int tid  = threadIdx.x;
    const int lane = tid & 63;
    const int wv   = tid >> 6;
    const int ln   = lane & 15;
    const int lg   = lane >> 4;
    const size_t m0 = (size_t)blockIdx.x * 64;

    sB[tid] = b_out[tid];

    f32x4 acc[16];
    #pragma unroll
    for (int nt = 0; nt < 16; ++nt) acc[nt] = (f32x4)(0.f);

    for (int kc = 0; kc < 4; ++kc) {
        if (kc) __syncthreads();
        #pragma unroll
        for (int it = 0; it < 4; ++it) {
            int g = tid + (it << 8);
            int row = g >> 4, f4 = g & 15;
            float4 v = *reinterpret_cast<const float4*>(
                io + (m0 + row) * 256 + kc * 64 + f4 * 4);
            ushort4 u;
            u.x = f2bf(v.x); u.y = f2bf(v.y); u.z = f2bf(v.z); u.w = f2bf(v.w);
            *reinterpret_cast<ushort4*>(&sA[row][f4 << 2]) = u;
        }
        #pragma unroll
        for (int i = 0; i < 16; ++i) {
            int f4 = ln + 16 * (i & 3);
            int kl = 16 * wv + lg + 4 * (i >> 2);
            float4 v = *reinterpret_cast<const float4*>(
                w_out + (size_t)(kc * 64 + kl) * 256 + f4 * 4);
            float vals[4] = {v.x, v.y, v.z, v.w};
            #pragma unroll
            for (int e0 = 0; e0 < 4; ++e0) {
                int e = (e0 + lane) & 3;
                sW2[f4 * 4 + e][kl] = f2bf(vals[e]);
            }
        }
        __syncthreads();

        #pragma unroll
        for (int ks = 0; ks < 2; ++ks) {
            bf16x8 a = ldsFrag(&sA[wv * 16 + ln][ks * 32 + lg * 8]);
            #pragma unroll
            for (int nt = 0; nt < 16; ++nt) {
                bf16x8 b = ldsFrag(&sW2[nt * 16 + ln][ks * 32 + lg * 8]);
                acc[nt] = MFMA16(a, b, acc[nt], 0, 0, 0);
            }
        }
    }

    #pragma unroll
    for (int nt = 0; nt < 16; ++nt) {
        float bias = sB[nt * 16 + ln];
        #pragma unroll
        for (int r = 0; r < 4; ++r) {
            int row = wv * 16 + lg * 4 + r;
            io[(m0 + row) * 256 + nt * 16 + ln] = acc[nt][r] + bias;
        }
    }
}

extern "C" void kernel_launch(void* const* d_in, const int* in_sizes, int n_in,
                              void* d_out, int out_size, void* d_ws, size_t ws_size,
                              hipStream_t stream) {
    const float* x     = (const float*)d_in[0];
    const float* w_qkv = (const float*)d_in[1];
    const float* w_out = (const float*)d_in[2];
    const float* b_out = (const float*)d_in[3];
    const float* pe    = (const float*)d_in[4];
    (void)in_sizes; (void)n_in; (void)out_size;

    float* out = (float*)d_out;

    if (ws_size >= (size_t)WS_NEED2) {
        unsigned short* wsT = (unsigned short*)d_ws;
        float* bias_tab = (float*)((char*)d_ws + 524288);
        unsigned short* wsO = wsT + O_SHORT_OFF;
        prep_kernel<<<dim3(257),  dim3(256), 0, stream>>>(w_qkv, w_out, pe, wsT, bias_tab);
        winattn8b  <<<dim3(4096), dim3(256), 0, stream>>>(x, wsT, bias_tab, wsO);
        proj5b     <<<dim3(1024), dim3(256), 0, stream>>>(wsO, wsT + WOUTT_SHORT_OFF, b_out, out);
    } else {
        winattn_fb <<<dim3(8192), dim3(256), 0, stream>>>(x, w_qkv, pe, out);
        proj_fb    <<<dim3(1024), dim3(256), 0, stream>>>(out, w_out, b_out);
    }
}